// Round 9
// baseline (1657.028 us; speedup 1.0000x reference)
//
#include <hip/hip_runtime.h>
#include <hip/hip_bf16.h>
#include <stdint.h>
#include <math.h>

// Problem constants
#define N_TOK 48000     // 32*1500
#define DIMS  256
#define KCB   2048
// 1-pass bf16 approx score error: std ~4.3e-3/score, diff std ~6e-3,
// sub-Gaussian (sum of 512 bounded terms). W = 0.08 = 13 sigma.
// True winner has approx >= best - W. Candidates = per-tile top-3 within
// window; only ">=4 in-window in ONE 256-code tile" needs a full re-scan.
#define WND 0.08f

typedef __attribute__((ext_vector_type(8))) short bf16x8;
typedef __attribute__((ext_vector_type(4))) float f32x4;
typedef __attribute__((ext_vector_type(8))) unsigned short u16x8;

// ---------------- bf16 helpers (explicit RNE) ----------------
__device__ __forceinline__ unsigned short bf16rn(float f) {
  uint32_t u = __float_as_uint(f);
  uint32_t r = (u + 0x7FFFu + ((u >> 16) & 1u)) >> 16;
  return (unsigned short)r;
}

// ---------------- Threefry-2x32 (matches jax._src.prng, partitionable) ----------------
__device__ inline void tf2x32(uint32_t k0, uint32_t k1, uint32_t c0, uint32_t c1,
                              uint32_t& o0, uint32_t& o1) {
  uint32_t ks2 = k0 ^ k1 ^ 0x1BD11BDAu;
  uint32_t x0 = c0 + k0, x1 = c1 + k1;
#define TF_R(r) { x0 += x1; x1 = (x1 << (r)) | (x1 >> (32 - (r))); x1 ^= x0; }
  TF_R(13) TF_R(15) TF_R(26) TF_R(6)
  x0 += k1; x1 += ks2 + 1u;
  TF_R(17) TF_R(29) TF_R(16) TF_R(24)
  x0 += ks2; x1 += k0 + 2u;
  TF_R(13) TF_R(15) TF_R(26) TF_R(6)
  x0 += k0; x1 += k1 + 3u;
  TF_R(17) TF_R(29) TF_R(16) TF_R(24)
  x0 += k1; x1 += ks2 + 4u;
  TF_R(13) TF_R(15) TF_R(26) TF_R(6)
  x0 += ks2; x1 += k0 + 5u;
#undef TF_R
  o0 = x0; o1 = x1;
}

__device__ inline void get_round_key(int round, uint32_t& ka, uint32_t& kb) {
  const uint32_t b0 = 0u, b1 = 1u;  // jax.random.key(1) -> (0,1)
  uint32_t K1a, K1b, S1a, S1b;
  tf2x32(b0, b1, 0u, 0u, K1a, K1b);
  tf2x32(b0, b1, 0u, 1u, S1a, S1b);
  if (round == 1) { ka = S1a; kb = S1b; return; }
  uint32_t S2a, S2b;
  tf2x32(K1a, K1b, 0u, 1u, S2a, S2b);
  ka = S2a; kb = S2b;
}

__device__ inline uint32_t gen_key(int round, uint32_t i) {
  uint32_t ka, kb, o0, o1;
  get_round_key(round, ka, kb);
  tf2x32(ka, kb, 0u, i, o0, o1);
  return o0 ^ o1;
}

// ---------------- top-3 (values + indices) primitives ----------------
__device__ __forceinline__ bool gtr(float v1, int k1, float v2, int k2) {
  return (v1 > v2) || (v1 == v2 && k1 < k2);
}
__device__ __forceinline__ void ins3i(float& b, float& s, float& t,
                                      int& kb, int& ks, int& kt,
                                      float v, int k) {
  if (gtr(v, k, b, kb))      { t = s; kt = ks; s = b; ks = kb; b = v; kb = k; }
  else if (gtr(v, k, s, ks)) { t = s; kt = ks; s = v; ks = k; }
  else if (gtr(v, k, t, kt)) { t = v; kt = k; }
}

// ---------------- global_load_lds wrapper (16B) ----------------
__device__ __forceinline__ void gload_lds16(const void* g, void* l) {
  __builtin_amdgcn_global_load_lds(
      (const __attribute__((address_space(1))) uint32_t*)g,
      (__attribute__((address_space(3))) uint32_t*)l, 16, 0, 0);
}

// ---------------- e2[k] = sum(embed[k]^2), f32 + f64 ----------------
__global__ void e2_kernel(const float* __restrict__ embed, float* __restrict__ e2,
                          double* __restrict__ e2d) {
  int k = blockIdx.x * blockDim.x + threadIdx.x;
  if (k >= KCB) return;
  const float4* er = (const float4*)(embed + (size_t)k * DIMS);
  float s = 0.f;
  double sd = 0.0;
  for (int c = 0; c < DIMS / 4; ++c) {
    float4 v = er[c];
    s = fmaf(v.x, v.x, s); s = fmaf(v.y, v.y, s);
    s = fmaf(v.z, v.z, s); s = fmaf(v.w, v.w, s);
    sd += (double)v.x * v.x + (double)v.y * v.y
        + (double)v.z * v.z + (double)v.w * v.w;
  }
  e2[k] = s;
  e2d[k] = sd;
}

// ---------------- f32 -> bf16 (RNE) ----------------
__global__ void split_hi(const float* __restrict__ x, unsigned short* __restrict__ hi,
                         int n8) {
  int i = blockIdx.x * blockDim.x + threadIdx.x;
  if (i >= n8) return;
  float4 a = ((const float4*)x)[i * 2];
  float4 b = ((const float4*)x)[i * 2 + 1];
  float v[8] = {a.x, a.y, a.z, a.w, b.x, b.y, b.z, b.w};
  u16x8 h;
#pragma unroll
  for (int j = 0; j < 8; ++j) h[j] = bf16rn(v[j]);
  *(u16x8*)&hi[(size_t)i * 8] = h;
}

// ---------------- MFMA distance top-3 (single bf16 pass, top-3 indices) ----------------
// approx score = 2*(xh.eh) - e2[k]; 128x256 tile, BK=32, 8 steps,
// double-buffered LDS. Bank swizzle (both-sides involution, rule 21):
// 64B rows = 4 chunks of 16B; physical chunk = logical ^ ((row>>1)&3).
__global__ __launch_bounds__(256, 2) void dist_mfma(
    const unsigned short* __restrict__ xh, const unsigned short* __restrict__ eh,
    const float* __restrict__ e2,
    float* __restrict__ pb, float* __restrict__ ps, float* __restrict__ pt,
    uint32_t* __restrict__ pkk, int* __restrict__ pk3)
{
  __shared__ short As[2][128 * 32];   // 2 x 8 KB
  __shared__ short Bs[2][256 * 32];   // 2 x 16 KB
  __shared__ float mbv[128], msv[128], mtv[128];
  __shared__ int mkb[128], mks[128], mkt[128];

  const int tid = threadIdx.x;
  const int lane = tid & 63, w = tid >> 6;
  const int wr = w >> 1, wc = w & 1;      // wave tile: 64 rows x 128 cols
  const int l15 = lane & 15, lg = lane >> 4;

  // XCD grouping: the 8 y-tiles sharing an x-tile get bids == same (mod 8),
  // spaced 8 apart -> same XCD L2 -> x-tile fetched from HBM once per XCD.
  int bx, by;
  {
    const int bid = blockIdx.x;
    if (bid < 2944) { int g = bid >> 6, r = bid & 63; bx = g * 8 + (r & 7); by = r >> 3; }
    else            { int t2 = bid - 2944; bx = 368 + (t2 % 7); by = t2 / 7; }
  }
  const int n0 = bx * 128;   // token tile base
  const int c0 = by * 256;   // code tile base

  f32x4 acc[4][8];
#pragma unroll
  for (int mf = 0; mf < 4; ++mf)
#pragma unroll
    for (int nf = 0; nf < 8; ++nf) acc[mf][nf] = (f32x4){0.f, 0.f, 0.f, 0.f};

  // stage step t into buffer t&1 (linear LDS dest; source pre-swizzled)
  auto stage = [&](int t) {
    const int d0 = t << 5;     // d-chunk of 32 shorts
    const int q = t & 1;
#pragma unroll
    for (int i = 0; i < 2; ++i) {
      const int c = i * 256 + tid;
      const int row = c >> 2;
      const int sc = ((c & 3) ^ ((row >> 1) & 3)) << 3;   // swizzled source chunk
      gload_lds16(xh + (size_t)(n0 + row) * DIMS + d0 + sc, (void*)&As[q][c * 8]);
    }
#pragma unroll
    for (int i = 0; i < 4; ++i) {
      const int c = i * 256 + tid;
      const int row = c >> 2;
      const int sc = ((c & 3) ^ ((row >> 1) & 3)) << 3;
      gload_lds16(eh + (size_t)(c0 + row) * DIMS + d0 + sc, (void*)&Bs[q][c * 8]);
    }
  };

  stage(0);
  __syncthreads();   // buf0 ready

#pragma unroll 1
  for (int t = 0; t < 8; ++t) {
    if (t < 7) stage(t + 1);         // issue next-step loads (overlap w/ compute)
    const int q = t & 1;
    bf16x8 af[4], bfv[8];
#pragma unroll
    for (int mf = 0; mf < 4; ++mf) {
      const int r = wr * 64 + mf * 16 + l15;
      af[mf] = *(const bf16x8*)&As[q][r * 32 + ((lg ^ ((r >> 1) & 3)) << 3)];
    }
#pragma unroll
    for (int nf = 0; nf < 8; ++nf) {
      const int r = wc * 128 + nf * 16 + l15;
      bfv[nf] = *(const bf16x8*)&Bs[q][r * 32 + ((lg ^ ((r >> 1) & 3)) << 3)];
    }
#pragma unroll
    for (int mf = 0; mf < 4; ++mf)
#pragma unroll
      for (int nf = 0; nf < 8; ++nf)
        acc[mf][nf] = __builtin_amdgcn_mfma_f32_16x16x32_bf16(
            af[mf], bfv[nf], acc[mf][nf], 0, 0, 0);
    __syncthreads();                 // staged loads drained + rw hazards
  }

  float e2v[8];
#pragma unroll
  for (int nf = 0; nf < 8; ++nf) e2v[nf] = e2[c0 + wc * 128 + nf * 16 + l15];

  float rb[16], rs[16], rt[16]; int rkb[16], rks[16], rkt[16];
#pragma unroll
  for (int mf = 0; mf < 4; ++mf) {
#pragma unroll
    for (int reg = 0; reg < 4; ++reg) {
      float b = fmaf(2.f, acc[mf][0][reg], -e2v[0]);
      float s = -INFINITY, t = -INFINITY;
      int kb = c0 + wc * 128 + l15, ks = 0x7fffffff, kt = 0x7fffffff;
#pragma unroll
      for (int nf = 1; nf < 8; ++nf) {
        float v = fmaf(2.f, acc[mf][nf][reg], -e2v[nf]);
        ins3i(b, s, t, kb, ks, kt, v, c0 + wc * 128 + nf * 16 + l15);
      }
#pragma unroll
      for (int m = 1; m <= 8; m <<= 1) {
        float ob = __shfl_xor(b, m), os = __shfl_xor(s, m), ot = __shfl_xor(t, m);
        int okb = __shfl_xor(kb, m), oks = __shfl_xor(ks, m), okt = __shfl_xor(kt, m);
        ins3i(b, s, t, kb, ks, kt, ob, okb);
        ins3i(b, s, t, kb, ks, kt, os, oks);
        ins3i(b, s, t, kb, ks, kt, ot, okt);
      }
      int q = mf * 4 + reg;
      rb[q] = b; rs[q] = s; rt[q] = t; rkb[q] = kb; rks[q] = ks; rkt[q] = kt;
    }
  }

  // wc=1 publishes to LDS, wc=0 merges + writes
  __syncthreads();
  if (wc == 1 && l15 == 0) {
#pragma unroll
    for (int mf = 0; mf < 4; ++mf)
#pragma unroll
      for (int reg = 0; reg < 4; ++reg) {
        int q = mf * 4 + reg;
        int r = wr * 64 + mf * 16 + lg * 4 + reg;
        mbv[r] = rb[q]; msv[r] = rs[q]; mtv[r] = rt[q];
        mkb[r] = rkb[q]; mks[r] = rks[q]; mkt[r] = rkt[q];
      }
  }
  __syncthreads();
  if (wc == 0 && l15 == 0) {
#pragma unroll
    for (int mf = 0; mf < 4; ++mf)
#pragma unroll
      for (int reg = 0; reg < 4; ++reg) {
        int q = mf * 4 + reg;
        int r = wr * 64 + mf * 16 + lg * 4 + reg;
        float b = rb[q], s = rs[q], t = rt[q];
        int kb = rkb[q], ks = rks[q], kt = rkt[q];
        ins3i(b, s, t, kb, ks, kt, mbv[r], mkb[r]);
        ins3i(b, s, t, kb, ks, kt, msv[r], mks[r]);
        ins3i(b, s, t, kb, ks, kt, mtv[r], mkt[r]);
        size_t o = (size_t)by * N_TOK + n0 + r;
        pb[o] = b; ps[o] = s; pt[o] = t;
        pkk[o] = ((uint32_t)kb << 16) | ((uint32_t)ks & 0xffffu);
        pk3[o] = kt;
      }
  }
}

// ---------------- merge 8 column-tile partials + candidate collection ----------------
__global__ void merge8(const float* __restrict__ pb, const float* __restrict__ ps,
                       const float* __restrict__ pt, const uint32_t* __restrict__ pkk,
                       const int* __restrict__ pk3,
                       int* __restrict__ ind,
                       int* __restrict__ candRows, int* __restrict__ candIdx,
                       int* __restrict__ candCnt, int* __restrict__ listC,
                       uint32_t* __restrict__ cntA, uint32_t* __restrict__ cntC) {
  int n = blockIdx.x * blockDim.x + threadIdx.x;
  if (n >= N_TOK) return;
  float tb[8], tsv[8], ttv[8]; int tkb[8], tks[8], tkt[8];
#pragma unroll
  for (int tt = 0; tt < 8; ++tt) {
    size_t o = (size_t)tt * N_TOK + n;
    tb[tt] = pb[o]; tsv[tt] = ps[o]; ttv[tt] = pt[o];
    uint32_t kk = pkk[o];
    tkb[tt] = (int)(kk >> 16); tks[tt] = (int)(kk & 0xffffu); tkt[tt] = pk3[o];
  }
  float b = tb[0]; int kb = tkb[0];
#pragma unroll
  for (int tt = 1; tt < 8; ++tt)
    if (gtr(tb[tt], tkb[tt], b, kb)) { b = tb[tt]; kb = tkb[tt]; }
  ind[n] = kb;   // provisional winner (final unless refined below)
  const float thr = b - WND;
  int m = 0; bool full = false;
#pragma unroll
  for (int tt = 0; tt < 8; ++tt) {
    m += (tb[tt] >= thr) + (tsv[tt] >= thr) + (ttv[tt] >= thr);
    full = full || (ttv[tt] >= thr);   // tile's 4th could hide in-window
  }
  if (full) {
    listC[atomicAdd(cntC, 1u)] = n;
  } else if (m > 1) {
    uint32_t i = atomicAdd(cntA, 1u);
    candRows[i] = n; candCnt[i] = m;
    int j = 0;
#pragma unroll
    for (int tt = 0; tt < 8; ++tt) {
      if (tb[tt]  >= thr) candIdx[(size_t)i * 24 + (j++)] = tkb[tt];
      if (tsv[tt] >= thr) candIdx[(size_t)i * 24 + (j++)] = tks[tt];
    }
  }
}

// ---------------- wave-per-row f64 candidate decider ----------------
__global__ void refine_cand(const float* __restrict__ x, const float* __restrict__ embed,
                            const double* __restrict__ e2d,
                            const int* __restrict__ candRows, const int* __restrict__ candIdx,
                            const int* __restrict__ candCnt, const uint32_t* __restrict__ cntA,
                            int* __restrict__ ind) {
  const uint32_t nA = cntA[0];
  const int lane = threadIdx.x & 63;
  const uint32_t wid = (blockIdx.x * blockDim.x + threadIdx.x) >> 6;
  const uint32_t nw = (gridDim.x * blockDim.x) >> 6;
  for (uint32_t i = wid; i < nA; i += nw) {
    const int n = candRows[i];
    const int m = candCnt[i];
    float4 xv = ((const float4*)x)[(size_t)n * 64 + lane];
    double best = -1e300; int bk = 0x7fffffff;
    for (int j = 0; j < m; ++j) {
      int k = candIdx[(size_t)i * 24 + j];
      float4 e4 = ((const float4*)embed)[(size_t)k * 64 + lane];
      double d = (double)xv.x * e4.x + (double)xv.y * e4.y
               + (double)xv.z * e4.z + (double)xv.w * e4.w;
#pragma unroll
      for (int mm = 1; mm < 64; mm <<= 1) d += __shfl_xor(d, mm);
      double v = 2.0 * d - e2d[k];
      if (v > best || (v == best && k < bk)) { best = v; bk = k; }
    }
    if (lane == 0) ind[n] = bk;
  }
}

// ---------------- full f64 re-scan, one row per block (rare) ----------------
__global__ void refine_fullC(const float* __restrict__ x, const float* __restrict__ embed,
                             const double* __restrict__ e2d,
                             const int* __restrict__ listC, const uint32_t* __restrict__ cntC,
                             int* __restrict__ ind) {
  __shared__ double xd[DIMS];
  __shared__ double rv[256];
  __shared__ int    rk[256];
  const int tid = threadIdx.x;
  const uint32_t nC = cntC[0];
  for (uint32_t it = blockIdx.x; it < nC; it += gridDim.x) {
    const int n = listC[it];
    __syncthreads();
    xd[tid] = (double)x[(size_t)n * DIMS + tid];
    __syncthreads();
    double best = -1e300; int bk = 0x7fffffff;
    for (int k = tid; k < KCB; k += 256) {
      const float4* er = (const float4*)(embed + (size_t)k * DIMS);
      double a0 = 0.0, a1 = 0.0, a2 = 0.0, a3 = 0.0;   // ILP-4 chains
      for (int c = 0; c < 64; c += 4) {
        float4 ea = er[c], eb = er[c + 1], ec = er[c + 2], ed = er[c + 3];
        int d = c * 4;
        a0 += xd[d + 0] * ea.x + xd[d + 1] * ea.y + xd[d + 2] * ea.z + xd[d + 3] * ea.w;
        a1 += xd[d + 4] * eb.x + xd[d + 5] * eb.y + xd[d + 6] * eb.z + xd[d + 7] * eb.w;
        a2 += xd[d + 8] * ec.x + xd[d + 9] * ec.y + xd[d + 10] * ec.z + xd[d + 11] * ec.w;
        a3 += xd[d + 12] * ed.x + xd[d + 13] * ed.y + xd[d + 14] * ed.z + xd[d + 15] * ed.w;
      }
      double v = 2.0 * (a0 + a1 + a2 + a3) - e2d[k];
      if (v > best || (v == best && k < bk)) { best = v; bk = k; }
    }
    rv[tid] = best; rk[tid] = bk;
    __syncthreads();
    for (int s = 128; s > 0; s >>= 1) {
      if (tid < s) {
        double v2 = rv[tid + s]; int k2 = rk[tid + s];
        if (v2 > rv[tid] || (v2 == rv[tid] && k2 < rk[tid])) { rv[tid] = v2; rk[tid] = k2; }
      }
      __syncthreads();
    }
    if (tid == 0) ind[n] = rk[0];
  }
}

// ---------------- quantize gather + codes + counts + embed_sum ----------------
__global__ void gather_scatter(const float* __restrict__ x, const float* __restrict__ embed,
                               const int* __restrict__ ind,
                               float* __restrict__ outq, float* __restrict__ outcodes,
                               float* __restrict__ counts, float* __restrict__ esum) {
  int idx = blockIdx.x * blockDim.x + threadIdx.x;   // over N_TOK*64 float4s
  if (idx >= N_TOK * 64) return;
  int n = idx >> 6, c = idx & 63;
  int k = ind[n];
  float4 e = ((const float4*)embed)[(size_t)k * 64 + c];
  ((float4*)outq)[idx] = e;
  float4 xv = ((const float4*)x)[idx];
  float* base = esum + (size_t)k * DIMS + c * 4;
  atomicAdd(base + 0, xv.x); atomicAdd(base + 1, xv.y);
  atomicAdd(base + 2, xv.z); atomicAdd(base + 3, xv.w);
  if (c == 0) { outcodes[n] = (float)k; atomicAdd(&counts[k], 1.0f); }
}

// ---------------- new_cluster_size + n-sum + expired ----------------
__global__ void ema_stats(const float* __restrict__ cs, const float* __restrict__ counts,
                          float* __restrict__ out_ncs, int* __restrict__ expired,
                          double* __restrict__ nsum) {
  __shared__ double sd[1024];
  int tid = threadIdx.x;
  double local = 0.0;
  for (int k = tid; k < KCB; k += 1024) {
    double v = 0.99 * (double)cs[k] + 0.01 * (double)counts[k];
    out_ncs[k] = (float)v;
    expired[k] = (v < 2.0) ? 1 : 0;
    local += v;
  }
  sd[tid] = local; __syncthreads();
  for (int s = 512; s > 0; s >>= 1) { if (tid < s) sd[tid] += sd[tid + s]; __syncthreads(); }
  if (tid == 0) nsum[0] = sd[0];
}

// ---------------- new_embed_avg + new_embed ----------------
__global__ void final_embed(const float* __restrict__ x, const float* __restrict__ cs,
                            const float* __restrict__ counts,
                            const float* __restrict__ eavg, const float* __restrict__ esum,
                            const int* __restrict__ expired, const double* __restrict__ nsum,
                            const uint32_t* __restrict__ perm,
                            float* __restrict__ out_eavg, float* __restrict__ out_ne) {
  int idx = blockIdx.x * blockDim.x + threadIdx.x;   // over KCB*64 float4s
  if (idx >= KCB * 64) return;
  int k = idx >> 6, c = idx & 63;
  float4 ea = ((const float4*)eavg)[idx];
  float4 es = ((const float4*)esum)[idx];
  double ax = 0.99 * (double)ea.x + 0.01 * (double)es.x;
  double ay = 0.99 * (double)ea.y + 0.01 * (double)es.y;
  double az = 0.99 * (double)ea.z + 0.01 * (double)es.z;
  double aw = 0.99 * (double)ea.w + 0.01 * (double)es.w;
  float4 nv; nv.x = (float)ax; nv.y = (float)ay; nv.z = (float)az; nv.w = (float)aw;
  ((float4*)out_eavg)[idx] = nv;
  float4 r;
  if (expired[k]) {
    r = ((const float4*)x)[(size_t)perm[k] * 64 + c];
  } else {
    double ncs = 0.99 * (double)cs[k] + 0.01 * (double)counts[k];
    double n = nsum[0];
    double sm = (ncs + 1e-5) / (n + 2048.0 * 1e-5) * n;
    r.x = (float)(ax / sm); r.y = (float)(ay / sm);
    r.z = (float)(az / sm); r.w = (float)(aw / sm);
  }
  ((float4*)out_ne)[idx] = r;
}

// ---------------- permutation pipeline (stable sort by random keys) ----------------
__global__ void keys_round(int round, uint32_t* __restrict__ keys,
                           uint32_t* __restrict__ vals_init, uint32_t* __restrict__ bcount) {
  int i = blockIdx.x * blockDim.x + threadIdx.x;
  if (i >= N_TOK) return;
  uint32_t key = gen_key(round, (uint32_t)i);
  keys[i] = key;
  if (vals_init) vals_init[i] = (uint32_t)i;
  atomicAdd(&bcount[key >> 21], 1u);
}

__global__ void scan2048(const uint32_t* __restrict__ in, uint32_t* __restrict__ out,
                         uint32_t* __restrict__ cursor_zero) {
  __shared__ uint32_t buf[2][2048];
  int t = threadIdx.x;   // 1024
  for (int q = 0; q < 2; ++q) buf[0][t + q * 1024] = in[t + q * 1024];
  cursor_zero[t] = 0; cursor_zero[t + 1024] = 0;
  __syncthreads();
  int src = 0;
  for (int off = 1; off < 2048; off <<= 1) {
    for (int q = 0; q < 2; ++q) {
      int i = t + q * 1024;
      uint32_t v = buf[src][i];
      if (i >= off) v += buf[src][i - off];
      buf[src ^ 1][i] = v;
    }
    src ^= 1; __syncthreads();
  }
  for (int q = 0; q < 2; ++q) {
    int i = t + q * 1024;
    out[i] = buf[src][i] - in[i];   // exclusive
  }
}

__global__ void scatter_buckets(const uint32_t* __restrict__ keys, const uint32_t* __restrict__ vals_in,
                                const uint32_t* __restrict__ bbase, uint32_t* __restrict__ cursor,
                                uint32_t* __restrict__ bkey, uint32_t* __restrict__ bval,
                                uint32_t* __restrict__ bpos) {
  int i = blockIdx.x * blockDim.x + threadIdx.x;
  if (i >= N_TOK) return;
  uint32_t k = keys[i];
  uint32_t b = k >> 21;
  uint32_t p = atomicAdd(&cursor[b], 1u);
  uint32_t s = bbase[b] + p;
  bkey[s] = k; bval[s] = vals_in[i]; bpos[s] = (uint32_t)i;
}

__global__ void rank_buckets(const uint32_t* __restrict__ bkey, const uint32_t* __restrict__ bval,
                             const uint32_t* __restrict__ bpos, const uint32_t* __restrict__ bbase,
                             const uint32_t* __restrict__ bcount, uint32_t* __restrict__ out_vals) {
  int b = blockIdx.x;
  uint32_t base = bbase[b], cnt = bcount[b];
  for (uint32_t t = threadIdx.x; t < cnt; t += blockDim.x) {
    uint32_t k = bkey[base + t], p = bpos[base + t];
    uint32_t r = 0;
    for (uint32_t j = 0; j < cnt; ++j) {
      uint32_t kj = bkey[base + j], pj = bpos[base + j];
      r += (kj < k) | ((kj == k) & (pj < p));
    }
    out_vals[base + r] = bval[base + t];
  }
}

// ---------------- launch ----------------
extern "C" void kernel_launch(void* const* d_in, const int* in_sizes, int n_in,
                              void* d_out, int out_size, void* d_ws, size_t ws_size,
                              hipStream_t stream) {
  const float* x     = (const float*)d_in[0];
  const float* embed = (const float*)d_in[1];
  const float* cs    = (const float*)d_in[2];
  const float* eavg  = (const float*)d_in[3];

  float* out = (float*)d_out;
  float* outQ    = out;                  // 12,288,000
  float* outC    = out + 12288000;       // 48,000
  float* outNCS  = out + 12336000;       // 2,048
  float* outEAVG = out + 12338048;       // 524,288
  float* outNE   = out + 12862336;       // 524,288

  char* w = (char*)d_ws;
  size_t off = 0;
  auto alloc = [&](size_t bytes) -> void* {
    void* p = w + off; off += (bytes + 255) & ~(size_t)255; return p;
  };
  unsigned short* xh = (unsigned short*)alloc((size_t)N_TOK * DIMS * 2);
  unsigned short* eh = (unsigned short*)alloc((size_t)KCB * DIMS * 2);
  float*    e2      = (float*)alloc(KCB * 4);
  double*   e2d     = (double*)alloc(KCB * 8);
  float*    counts  = (float*)alloc(KCB * 4);
  float*    esum    = (float*)alloc((size_t)KCB * DIMS * 4);   // contiguous after counts
  float*    pbest   = (float*)alloc((size_t)8 * N_TOK * 4);
  float*    psecond = (float*)alloc((size_t)8 * N_TOK * 4);
  float*    pthird  = (float*)alloc((size_t)8 * N_TOK * 4);
  uint32_t* pkk     = (uint32_t*)alloc((size_t)8 * N_TOK * 4);
  int*      pk3     = (int*)alloc((size_t)8 * N_TOK * 4);
  int*      ind     = (int*)alloc(N_TOK * 4);
  int*      candRows= (int*)alloc(N_TOK * 4);
  int*      candCnt = (int*)alloc(N_TOK * 4);
  int*      candIdx = (int*)alloc((size_t)N_TOK * 24 * 4);
  int*      listC   = (int*)alloc(N_TOK * 4);
  uint32_t* cntAB   = (uint32_t*)alloc(256);      // [0]=cand rows, [1]=listC
  double*   nsum    = (double*)alloc(256);
  int*      expired = (int*)alloc(KCB * 4);
  uint32_t* keys    = (uint32_t*)alloc(N_TOK * 4);
  uint32_t* valsA   = (uint32_t*)alloc(N_TOK * 4);
  uint32_t* bkey    = (uint32_t*)alloc(N_TOK * 4);
  uint32_t* bval    = (uint32_t*)alloc(N_TOK * 4);
  uint32_t* bpos    = (uint32_t*)alloc(N_TOK * 4);
  uint32_t* valsB   = (uint32_t*)alloc(N_TOK * 4);
  uint32_t* bcount  = (uint32_t*)alloc(KCB * 4);
  uint32_t* bbase   = (uint32_t*)alloc(KCB * 4);
  uint32_t* cursor  = (uint32_t*)alloc(KCB * 4);

  // zero accumulators (counts+esum contiguous), tie counters, bucket counts
  hipMemsetAsync(counts, 0, KCB * 4 + (size_t)KCB * DIMS * 4, stream);
  hipMemsetAsync(cntAB, 0, 256, stream);
  hipMemsetAsync(bcount, 0, KCB * 4, stream);

  e2_kernel<<<8, 256, 0, stream>>>(embed, e2, e2d);
  split_hi<<<6000, 256, 0, stream>>>(x, xh, N_TOK * DIMS / 8);
  split_hi<<<256, 256, 0, stream>>>(embed, eh, KCB * DIMS / 8);

  dist_mfma<<<3000, 256, 0, stream>>>(xh, eh, e2, pbest, psecond, pthird, pkk, pk3);
  merge8<<<188, 256, 0, stream>>>(pbest, psecond, pthird, pkk, pk3,
                                  ind, candRows, candIdx, candCnt, listC,
                                  &cntAB[0], &cntAB[1]);
  refine_cand<<<512, 256, 0, stream>>>(x, embed, e2d, candRows, candIdx, candCnt,
                                       &cntAB[0], ind);
  refine_fullC<<<1024, 256, 0, stream>>>(x, embed, e2d, listC, &cntAB[1], ind);

  gather_scatter<<<12000, 256, 0, stream>>>(x, embed, ind, outQ, outC, counts, esum);
  ema_stats<<<1, 1024, 0, stream>>>(cs, counts, outNCS, expired, nsum);

  // permutation: round 1 (vals = iota)
  keys_round<<<188, 256, 0, stream>>>(1, keys, valsA, bcount);
  scan2048<<<1, 1024, 0, stream>>>(bcount, bbase, cursor);
  scatter_buckets<<<188, 256, 0, stream>>>(keys, valsA, bbase, cursor, bkey, bval, bpos);
  rank_buckets<<<2048, 64, 0, stream>>>(bkey, bval, bpos, bbase, bcount, valsB);
  // round 2 (vals = round-1 output)
  hipMemsetAsync(bcount, 0, KCB * 4, stream);
  keys_round<<<188, 256, 0, stream>>>(2, keys, nullptr, bcount);
  scan2048<<<1, 1024, 0, stream>>>(bcount, bbase, cursor);
  scatter_buckets<<<188, 256, 0, stream>>>(keys, valsB, bbase, cursor, bkey, bval, bpos);
  rank_buckets<<<2048, 64, 0, stream>>>(bkey, bval, bpos, bbase, bcount, valsA);

  final_embed<<<512, 256, 0, stream>>>(x, cs, counts, eavg, esum, expired, nsum,
                                       valsA, outEAVG, outNE);
}

// Round 10
// 527.810 us; speedup vs baseline: 3.1394x; 3.1394x over previous
//
#include <hip/hip_runtime.h>
#include <hip/hip_bf16.h>
#include <stdint.h>
#include <math.h>

// Problem constants
#define N_TOK 48000     // 32*1500
#define DIMS  256
#define KCB   2048
// 1-pass bf16 approx score error: std ~4.3e-3/score, diff std ~6e-3,
// sub-Gaussian. W = 0.08 ~ 13 sigma. True winner's approx >= best - W.
// Candidates = per-tile top-2 indices with value in window; if any tile's
// THIRD value is in window the winner may be unstored -> full f64 re-scan.
#define WND 0.08f

typedef __attribute__((ext_vector_type(8))) short bf16x8;
typedef __attribute__((ext_vector_type(4))) float f32x4;
typedef __attribute__((ext_vector_type(8))) unsigned short u16x8;

// ---------------- bf16 helpers (explicit RNE) ----------------
__device__ __forceinline__ unsigned short bf16rn(float f) {
  uint32_t u = __float_as_uint(f);
  uint32_t r = (u + 0x7FFFu + ((u >> 16) & 1u)) >> 16;
  return (unsigned short)r;
}

// ---------------- Threefry-2x32 (matches jax._src.prng, partitionable) ----------------
__device__ inline void tf2x32(uint32_t k0, uint32_t k1, uint32_t c0, uint32_t c1,
                              uint32_t& o0, uint32_t& o1) {
  uint32_t ks2 = k0 ^ k1 ^ 0x1BD11BDAu;
  uint32_t x0 = c0 + k0, x1 = c1 + k1;
#define TF_R(r) { x0 += x1; x1 = (x1 << (r)) | (x1 >> (32 - (r))); x1 ^= x0; }
  TF_R(13) TF_R(15) TF_R(26) TF_R(6)
  x0 += k1; x1 += ks2 + 1u;
  TF_R(17) TF_R(29) TF_R(16) TF_R(24)
  x0 += ks2; x1 += k0 + 2u;
  TF_R(13) TF_R(15) TF_R(26) TF_R(6)
  x0 += k0; x1 += k1 + 3u;
  TF_R(17) TF_R(29) TF_R(16) TF_R(24)
  x0 += k1; x1 += ks2 + 4u;
  TF_R(13) TF_R(15) TF_R(26) TF_R(6)
  x0 += ks2; x1 += k0 + 5u;
#undef TF_R
  o0 = x0; o1 = x1;
}

__device__ inline void get_round_key(int round, uint32_t& ka, uint32_t& kb) {
  const uint32_t b0 = 0u, b1 = 1u;  // jax.random.key(1) -> (0,1)
  uint32_t K1a, K1b, S1a, S1b;
  tf2x32(b0, b1, 0u, 0u, K1a, K1b);
  tf2x32(b0, b1, 0u, 1u, S1a, S1b);
  if (round == 1) { ka = S1a; kb = S1b; return; }
  uint32_t S2a, S2b;
  tf2x32(K1a, K1b, 0u, 1u, S2a, S2b);
  ka = S2a; kb = S2b;
}

__device__ inline uint32_t gen_key(int round, uint32_t i) {
  uint32_t ka, kb, o0, o1;
  get_round_key(round, ka, kb);
  tf2x32(ka, kb, 0u, i, o0, o1);
  return o0 ^ o1;
}

// ---------------- top-3 (values) + top-2 (indices) primitives ----------------
__device__ __forceinline__ bool gtr(float v1, int k1, float v2, int k2) {
  return (v1 > v2) || (v1 == v2 && k1 < k2);
}
__device__ __forceinline__ void ins3(float& b, float& s, float& t, int& kb, int& ks,
                                     float v, int k) {
  if (gtr(v, k, b, kb))      { t = s; s = b; ks = kb; b = v; kb = k; }
  else if (gtr(v, k, s, ks)) { t = s; s = v; ks = k; }
  else t = fmaxf(t, v);
}
// merge two top-3 sets (disjoint code sets)
__device__ __forceinline__ void mrg3(float& b, float& s, float& t, int& kb, int& ks,
                                     float ob, float os, float ot, int okb, int oks) {
  float nb, ns, m2; int nkb, nks;
  if (gtr(b, kb, ob, okb)) {
    nb = b; nkb = kb;
    if (gtr(s, ks, ob, okb)) { ns = s; nks = ks; m2 = ob; }
    else { ns = ob; nks = okb; m2 = fmaxf(s, os); }
  } else {
    nb = ob; nkb = okb;
    if (gtr(os, oks, b, kb)) { ns = os; nks = oks; m2 = b; }
    else { ns = b; nks = kb; m2 = fmaxf(os, s); }
  }
  t = fmaxf(m2, fmaxf(t, ot));
  b = nb; s = ns; kb = nkb; ks = nks;
}

// ---------------- global_load_lds wrapper (16B) ----------------
__device__ __forceinline__ void gload_lds16(const void* g, void* l) {
  __builtin_amdgcn_global_load_lds(
      (const __attribute__((address_space(1))) uint32_t*)g,
      (__attribute__((address_space(3))) uint32_t*)l, 16, 0, 0);
}

// ---------------- e2[k] = sum(embed[k]^2), f32 + f64 ----------------
__global__ void e2_kernel(const float* __restrict__ embed, float* __restrict__ e2,
                          double* __restrict__ e2d) {
  int k = blockIdx.x * blockDim.x + threadIdx.x;
  if (k >= KCB) return;
  const float4* er = (const float4*)(embed + (size_t)k * DIMS);
  float s = 0.f;
  double sd = 0.0;
  for (int c = 0; c < DIMS / 4; ++c) {
    float4 v = er[c];
    s = fmaf(v.x, v.x, s); s = fmaf(v.y, v.y, s);
    s = fmaf(v.z, v.z, s); s = fmaf(v.w, v.w, s);
    sd += (double)v.x * v.x + (double)v.y * v.y
        + (double)v.z * v.z + (double)v.w * v.w;
  }
  e2[k] = s;
  e2d[k] = sd;
}

// ---------------- f32 -> bf16 (RNE) ----------------
__global__ void split_hi(const float* __restrict__ x, unsigned short* __restrict__ hi,
                         int n8) {
  int i = blockIdx.x * blockDim.x + threadIdx.x;
  if (i >= n8) return;
  float4 a = ((const float4*)x)[i * 2];
  float4 b = ((const float4*)x)[i * 2 + 1];
  float v[8] = {a.x, a.y, a.z, a.w, b.x, b.y, b.z, b.w};
  u16x8 h;
#pragma unroll
  for (int j = 0; j < 8; ++j) h[j] = bf16rn(v[j]);
  *(u16x8*)&hi[(size_t)i * 8] = h;
}

// ---------------- MFMA distance top-3 (single bf16 pass) ----------------
// approx score = 2*(xh.eh) - e2[k]; 128x256 tile, BK=32, 8 steps,
// double-buffered LDS. Bank swizzle (both-sides involution, rule 21):
// 64B rows = 4 chunks of 16B; physical chunk = logical ^ ((row>>1)&3).
// Epilogue tracks top-3 VALUES + top-2 INDICES only (top-3-index tracking
// spilled acc to scratch in r9 -- VGPR cliff; the 3rd index is never needed).
__global__ __launch_bounds__(256, 2) void dist_mfma(
    const unsigned short* __restrict__ xh, const unsigned short* __restrict__ eh,
    const float* __restrict__ e2,
    float* __restrict__ pb, float* __restrict__ ps, float* __restrict__ pt,
    uint32_t* __restrict__ pkk)
{
  __shared__ short As[2][128 * 32];   // 2 x 8 KB
  __shared__ short Bs[2][256 * 32];   // 2 x 16 KB
  __shared__ float mbv[128], msv[128], mtv[128];
  __shared__ int mkb[128], mks[128];

  const int tid = threadIdx.x;
  const int lane = tid & 63, w = tid >> 6;
  const int wr = w >> 1, wc = w & 1;      // wave tile: 64 rows x 128 cols
  const int l15 = lane & 15, lg = lane >> 4;

  // XCD grouping: the 8 y-tiles sharing an x-tile get bids == same (mod 8),
  // spaced 8 apart -> same XCD L2 -> x-tile fetched from HBM once per XCD.
  int bx, by;
  {
    const int bid = blockIdx.x;
    if (bid < 2944) { int g = bid >> 6, r = bid & 63; bx = g * 8 + (r & 7); by = r >> 3; }
    else            { int t2 = bid - 2944; bx = 368 + (t2 % 7); by = t2 / 7; }
  }
  const int n0 = bx * 128;   // token tile base
  const int c0 = by * 256;   // code tile base

  f32x4 acc[4][8];
#pragma unroll
  for (int mf = 0; mf < 4; ++mf)
#pragma unroll
    for (int nf = 0; nf < 8; ++nf) acc[mf][nf] = (f32x4){0.f, 0.f, 0.f, 0.f};

  // stage step t into buffer t&1 (linear LDS dest; source pre-swizzled)
  auto stage = [&](int t) {
    const int d0 = t << 5;     // d-chunk of 32 shorts
    const int q = t & 1;
#pragma unroll
    for (int i = 0; i < 2; ++i) {
      const int c = i * 256 + tid;
      const int row = c >> 2;
      const int sc = ((c & 3) ^ ((row >> 1) & 3)) << 3;   // swizzled source chunk
      gload_lds16(xh + (size_t)(n0 + row) * DIMS + d0 + sc, (void*)&As[q][c * 8]);
    }
#pragma unroll
    for (int i = 0; i < 4; ++i) {
      const int c = i * 256 + tid;
      const int row = c >> 2;
      const int sc = ((c & 3) ^ ((row >> 1) & 3)) << 3;
      gload_lds16(eh + (size_t)(c0 + row) * DIMS + d0 + sc, (void*)&Bs[q][c * 8]);
    }
  };

  stage(0);
  __syncthreads();   // buf0 ready

#pragma unroll 1
  for (int t = 0; t < 8; ++t) {
    if (t < 7) stage(t + 1);         // issue next-step loads (overlap w/ compute)
    const int q = t & 1;
    bf16x8 af[4], bfv[8];
#pragma unroll
    for (int mf = 0; mf < 4; ++mf) {
      const int r = wr * 64 + mf * 16 + l15;
      af[mf] = *(const bf16x8*)&As[q][r * 32 + ((lg ^ ((r >> 1) & 3)) << 3)];
    }
#pragma unroll
    for (int nf = 0; nf < 8; ++nf) {
      const int r = wc * 128 + nf * 16 + l15;
      bfv[nf] = *(const bf16x8*)&Bs[q][r * 32 + ((lg ^ ((r >> 1) & 3)) << 3)];
    }
#pragma unroll
    for (int mf = 0; mf < 4; ++mf)
#pragma unroll
      for (int nf = 0; nf < 8; ++nf)
        acc[mf][nf] = __builtin_amdgcn_mfma_f32_16x16x32_bf16(
            af[mf], bfv[nf], acc[mf][nf], 0, 0, 0);
    __syncthreads();                 // staged loads drained + rw hazards
  }

  float e2v[8];
#pragma unroll
  for (int nf = 0; nf < 8; ++nf) e2v[nf] = e2[c0 + wc * 128 + nf * 16 + l15];

  float rb[16], rs[16], rt[16]; int rkb[16], rks[16];
#pragma unroll
  for (int mf = 0; mf < 4; ++mf) {
#pragma unroll
    for (int reg = 0; reg < 4; ++reg) {
      float b = fmaf(2.f, acc[mf][0][reg], -e2v[0]);
      float s = -INFINITY, t = -INFINITY;
      int kb = c0 + wc * 128 + l15, ks = 0x7fffffff;
#pragma unroll
      for (int nf = 1; nf < 8; ++nf) {
        float v = fmaf(2.f, acc[mf][nf][reg], -e2v[nf]);
        ins3(b, s, t, kb, ks, v, c0 + wc * 128 + nf * 16 + l15);
      }
#pragma unroll
      for (int m = 1; m <= 8; m <<= 1) {
        float ob = __shfl_xor(b, m), os = __shfl_xor(s, m), ot = __shfl_xor(t, m);
        int okb = __shfl_xor(kb, m), oks = __shfl_xor(ks, m);
        mrg3(b, s, t, kb, ks, ob, os, ot, okb, oks);
      }
      int q = mf * 4 + reg;
      rb[q] = b; rs[q] = s; rt[q] = t; rkb[q] = kb; rks[q] = ks;
    }
  }

  // wc=1 publishes to LDS, wc=0 merges + writes
  __syncthreads();
  if (wc == 1 && l15 == 0) {
#pragma unroll
    for (int mf = 0; mf < 4; ++mf)
#pragma unroll
      for (int reg = 0; reg < 4; ++reg) {
        int q = mf * 4 + reg;
        int r = wr * 64 + mf * 16 + lg * 4 + reg;
        mbv[r] = rb[q]; msv[r] = rs[q]; mtv[r] = rt[q];
        mkb[r] = rkb[q]; mks[r] = rks[q];
      }
  }
  __syncthreads();
  if (wc == 0 && l15 == 0) {
#pragma unroll
    for (int mf = 0; mf < 4; ++mf)
#pragma unroll
      for (int reg = 0; reg < 4; ++reg) {
        int q = mf * 4 + reg;
        int r = wr * 64 + mf * 16 + lg * 4 + reg;
        float b = rb[q], s = rs[q], t = rt[q];
        int kb = rkb[q], ks = rks[q];
        mrg3(b, s, t, kb, ks, mbv[r], msv[r], mtv[r], mkb[r], mks[r]);
        size_t o = (size_t)by * N_TOK + n0 + r;
        pb[o] = b; ps[o] = s; pt[o] = t;
        pkk[o] = ((uint32_t)kb << 16) | ((uint32_t)ks & 0xffffu);
      }
  }
}

// ---------------- merge 8 column-tile partials + candidate collection ----------------
__global__ void merge8(const float* __restrict__ pb, const float* __restrict__ ps,
                       const float* __restrict__ pt, const uint32_t* __restrict__ pkk,
                       int* __restrict__ ind,
                       int* __restrict__ candRows, int* __restrict__ candIdx,
                       int* __restrict__ candCnt, int* __restrict__ listC,
                       uint32_t* __restrict__ cntA, uint32_t* __restrict__ cntC) {
  int n = blockIdx.x * blockDim.x + threadIdx.x;
  if (n >= N_TOK) return;
  float tb[8], tsv[8], ttv[8]; int tkb[8], tks[8];
#pragma unroll
  for (int tt = 0; tt < 8; ++tt) {
    size_t o = (size_t)tt * N_TOK + n;
    tb[tt] = pb[o]; tsv[tt] = ps[o]; ttv[tt] = pt[o];
    uint32_t kk = pkk[o];
    tkb[tt] = (int)(kk >> 16); tks[tt] = (int)(kk & 0xffffu);
  }
  float b = tb[0]; int kb = tkb[0];
#pragma unroll
  for (int tt = 1; tt < 8; ++tt)
    if (gtr(tb[tt], tkb[tt], b, kb)) { b = tb[tt]; kb = tkb[tt]; }
  ind[n] = kb;   // provisional winner (final unless refined below)
  const float thr = b - WND;
  int m = 0; bool full = false;
#pragma unroll
  for (int tt = 0; tt < 8; ++tt) {
    m += (tb[tt] >= thr) + (tsv[tt] >= thr);
    full = full || (ttv[tt] >= thr);   // a tile's unstored 3rd+ could be in-window
  }
  if (full) {
    listC[atomicAdd(cntC, 1u)] = n;
  } else if (m > 1) {
    uint32_t i = atomicAdd(cntA, 1u);
    candRows[i] = n; candCnt[i] = m;
    int j = 0;
#pragma unroll
    for (int tt = 0; tt < 8; ++tt) {
      if (tb[tt]  >= thr) candIdx[(size_t)i * 16 + (j++)] = tkb[tt];
      if (tsv[tt] >= thr) candIdx[(size_t)i * 16 + (j++)] = tks[tt];
    }
  }
}

// ---------------- wave-per-row f64 candidate decider ----------------
__global__ void refine_cand(const float* __restrict__ x, const float* __restrict__ embed,
                            const double* __restrict__ e2d,
                            const int* __restrict__ candRows, const int* __restrict__ candIdx,
                            const int* __restrict__ candCnt, const uint32_t* __restrict__ cntA,
                            int* __restrict__ ind) {
  const uint32_t nA = cntA[0];
  const int lane = threadIdx.x & 63;
  const uint32_t wid = (blockIdx.x * blockDim.x + threadIdx.x) >> 6;
  const uint32_t nw = (gridDim.x * blockDim.x) >> 6;
  for (uint32_t i = wid; i < nA; i += nw) {
    const int n = candRows[i];
    const int m = candCnt[i];
    float4 xv = ((const float4*)x)[(size_t)n * 64 + lane];
    double best = -1e300; int bk = 0x7fffffff;
    for (int j = 0; j < m; ++j) {
      int k = candIdx[(size_t)i * 16 + j];
      float4 e4 = ((const float4*)embed)[(size_t)k * 64 + lane];
      double d = (double)xv.x * e4.x + (double)xv.y * e4.y
               + (double)xv.z * e4.z + (double)xv.w * e4.w;
#pragma unroll
      for (int mm = 1; mm < 64; mm <<= 1) d += __shfl_xor(d, mm);
      double v = 2.0 * d - e2d[k];
      if (v > best || (v == best && k < bk)) { best = v; bk = k; }
    }
    if (lane == 0) ind[n] = bk;
  }
}

// ---------------- full f64 re-scan, one row per block (rare) ----------------
__global__ void refine_fullC(const float* __restrict__ x, const float* __restrict__ embed,
                             const double* __restrict__ e2d,
                             const int* __restrict__ listC, const uint32_t* __restrict__ cntC,
                             int* __restrict__ ind) {
  __shared__ double xd[DIMS];
  __shared__ double rv[256];
  __shared__ int    rk[256];
  const int tid = threadIdx.x;
  const uint32_t nC = cntC[0];
  for (uint32_t it = blockIdx.x; it < nC; it += gridDim.x) {
    const int n = listC[it];
    __syncthreads();
    xd[tid] = (double)x[(size_t)n * DIMS + tid];
    __syncthreads();
    double best = -1e300; int bk = 0x7fffffff;
    for (int k = tid; k < KCB; k += 256) {
      const float4* er = (const float4*)(embed + (size_t)k * DIMS);
      double a0 = 0.0, a1 = 0.0, a2 = 0.0, a3 = 0.0;   // ILP-4 chains
      for (int c = 0; c < 64; c += 4) {
        float4 ea = er[c], eb = er[c + 1], ec = er[c + 2], ed = er[c + 3];
        int d = c * 4;
        a0 += xd[d + 0] * ea.x + xd[d + 1] * ea.y + xd[d + 2] * ea.z + xd[d + 3] * ea.w;
        a1 += xd[d + 4] * eb.x + xd[d + 5] * eb.y + xd[d + 6] * eb.z + xd[d + 7] * eb.w;
        a2 += xd[d + 8] * ec.x + xd[d + 9] * ec.y + xd[d + 10] * ec.z + xd[d + 11] * ec.w;
        a3 += xd[d + 12] * ed.x + xd[d + 13] * ed.y + xd[d + 14] * ed.z + xd[d + 15] * ed.w;
      }
      double v = 2.0 * (a0 + a1 + a2 + a3) - e2d[k];
      if (v > best || (v == best && k < bk)) { best = v; bk = k; }
    }
    rv[tid] = best; rk[tid] = bk;
    __syncthreads();
    for (int s = 128; s > 0; s >>= 1) {
      if (tid < s) {
        double v2 = rv[tid + s]; int k2 = rk[tid + s];
        if (v2 > rv[tid] || (v2 == rv[tid] && k2 < rk[tid])) { rv[tid] = v2; rk[tid] = k2; }
      }
      __syncthreads();
    }
    if (tid == 0) ind[n] = rk[0];
  }
}

// ---------------- quantize gather + codes + counts + embed_sum ----------------
__global__ void gather_scatter(const float* __restrict__ x, const float* __restrict__ embed,
                               const int* __restrict__ ind,
                               float* __restrict__ outq, float* __restrict__ outcodes,
                               float* __restrict__ counts, float* __restrict__ esum) {
  int idx = blockIdx.x * blockDim.x + threadIdx.x;   // over N_TOK*64 float4s
  if (idx >= N_TOK * 64) return;
  int n = idx >> 6, c = idx & 63;
  int k = ind[n];
  float4 e = ((const float4*)embed)[(size_t)k * 64 + c];
  ((float4*)outq)[idx] = e;
  float4 xv = ((const float4*)x)[idx];
  float* base = esum + (size_t)k * DIMS + c * 4;
  atomicAdd(base + 0, xv.x); atomicAdd(base + 1, xv.y);
  atomicAdd(base + 2, xv.z); atomicAdd(base + 3, xv.w);
  if (c == 0) { outcodes[n] = (float)k; atomicAdd(&counts[k], 1.0f); }
}

// ---------------- new_cluster_size + n-sum + expired ----------------
__global__ void ema_stats(const float* __restrict__ cs, const float* __restrict__ counts,
                          float* __restrict__ out_ncs, int* __restrict__ expired,
                          double* __restrict__ nsum) {
  __shared__ double sd[1024];
  int tid = threadIdx.x;
  double local = 0.0;
  for (int k = tid; k < KCB; k += 1024) {
    double v = 0.99 * (double)cs[k] + 0.01 * (double)counts[k];
    out_ncs[k] = (float)v;
    expired[k] = (v < 2.0) ? 1 : 0;
    local += v;
  }
  sd[tid] = local; __syncthreads();
  for (int s = 512; s > 0; s >>= 1) { if (tid < s) sd[tid] += sd[tid + s]; __syncthreads(); }
  if (tid == 0) nsum[0] = sd[0];
}

// ---------------- new_embed_avg + new_embed ----------------
__global__ void final_embed(const float* __restrict__ x, const float* __restrict__ cs,
                            const float* __restrict__ counts,
                            const float* __restrict__ eavg, const float* __restrict__ esum,
                            const int* __restrict__ expired, const double* __restrict__ nsum,
                            const uint32_t* __restrict__ perm,
                            float* __restrict__ out_eavg, float* __restrict__ out_ne) {
  int idx = blockIdx.x * blockDim.x + threadIdx.x;   // over KCB*64 float4s
  if (idx >= KCB * 64) return;
  int k = idx >> 6, c = idx & 63;
  float4 ea = ((const float4*)eavg)[idx];
  float4 es = ((const float4*)esum)[idx];
  double ax = 0.99 * (double)ea.x + 0.01 * (double)es.x;
  double ay = 0.99 * (double)ea.y + 0.01 * (double)es.y;
  double az = 0.99 * (double)ea.z + 0.01 * (double)es.z;
  double aw = 0.99 * (double)ea.w + 0.01 * (double)es.w;
  float4 nv; nv.x = (float)ax; nv.y = (float)ay; nv.z = (float)az; nv.w = (float)aw;
  ((float4*)out_eavg)[idx] = nv;
  float4 r;
  if (expired[k]) {
    r = ((const float4*)x)[(size_t)perm[k] * 64 + c];
  } else {
    double ncs = 0.99 * (double)cs[k] + 0.01 * (double)counts[k];
    double n = nsum[0];
    double sm = (ncs + 1e-5) / (n + 2048.0 * 1e-5) * n;
    r.x = (float)(ax / sm); r.y = (float)(ay / sm);
    r.z = (float)(az / sm); r.w = (float)(aw / sm);
  }
  ((float4*)out_ne)[idx] = r;
}

// ---------------- permutation pipeline (stable sort by random keys) ----------------
__global__ void keys_round(int round, uint32_t* __restrict__ keys,
                           uint32_t* __restrict__ vals_init, uint32_t* __restrict__ bcount) {
  int i = blockIdx.x * blockDim.x + threadIdx.x;
  if (i >= N_TOK) return;
  uint32_t key = gen_key(round, (uint32_t)i);
  keys[i] = key;
  if (vals_init) vals_init[i] = (uint32_t)i;
  atomicAdd(&bcount[key >> 21], 1u);
}

__global__ void scan2048(const uint32_t* __restrict__ in, uint32_t* __restrict__ out,
                         uint32_t* __restrict__ cursor_zero) {
  __shared__ uint32_t buf[2][2048];
  int t = threadIdx.x;   // 1024
  for (int q = 0; q < 2; ++q) buf[0][t + q * 1024] = in[t + q * 1024];
  cursor_zero[t] = 0; cursor_zero[t + 1024] = 0;
  __syncthreads();
  int src = 0;
  for (int off = 1; off < 2048; off <<= 1) {
    for (int q = 0; q < 2; ++q) {
      int i = t + q * 1024;
      uint32_t v = buf[src][i];
      if (i >= off) v += buf[src][i - off];
      buf[src ^ 1][i] = v;
    }
    src ^= 1; __syncthreads();
  }
  for (int q = 0; q < 2; ++q) {
    int i = t + q * 1024;
    out[i] = buf[src][i] - in[i];   // exclusive
  }
}

__global__ void scatter_buckets(const uint32_t* __restrict__ keys, const uint32_t* __restrict__ vals_in,
                                const uint32_t* __restrict__ bbase, uint32_t* __restrict__ cursor,
                                uint32_t* __restrict__ bkey, uint32_t* __restrict__ bval,
                                uint32_t* __restrict__ bpos) {
  int i = blockIdx.x * blockDim.x + threadIdx.x;
  if (i >= N_TOK) return;
  uint32_t k = keys[i];
  uint32_t b = k >> 21;
  uint32_t p = atomicAdd(&cursor[b], 1u);
  uint32_t s = bbase[b] + p;
  bkey[s] = k; bval[s] = vals_in[i]; bpos[s] = (uint32_t)i;
}

__global__ void rank_buckets(const uint32_t* __restrict__ bkey, const uint32_t* __restrict__ bval,
                             const uint32_t* __restrict__ bpos, const uint32_t* __restrict__ bbase,
                             const uint32_t* __restrict__ bcount, uint32_t* __restrict__ out_vals) {
  int b = blockIdx.x;
  uint32_t base = bbase[b], cnt = bcount[b];
  for (uint32_t t = threadIdx.x; t < cnt; t += blockDim.x) {
    uint32_t k = bkey[base + t], p = bpos[base + t];
    uint32_t r = 0;
    for (uint32_t j = 0; j < cnt; ++j) {
      uint32_t kj = bkey[base + j], pj = bpos[base + j];
      r += (kj < k) | ((kj == k) & (pj < p));
    }
    out_vals[base + r] = bval[base + t];
  }
}

// ---------------- launch ----------------
extern "C" void kernel_launch(void* const* d_in, const int* in_sizes, int n_in,
                              void* d_out, int out_size, void* d_ws, size_t ws_size,
                              hipStream_t stream) {
  const float* x     = (const float*)d_in[0];
  const float* embed = (const float*)d_in[1];
  const float* cs    = (const float*)d_in[2];
  const float* eavg  = (const float*)d_in[3];

  float* out = (float*)d_out;
  float* outQ    = out;                  // 12,288,000
  float* outC    = out + 12288000;       // 48,000
  float* outNCS  = out + 12336000;       // 2,048
  float* outEAVG = out + 12338048;       // 524,288
  float* outNE   = out + 12862336;       // 524,288

  char* w = (char*)d_ws;
  size_t off = 0;
  auto alloc = [&](size_t bytes) -> void* {
    void* p = w + off; off += (bytes + 255) & ~(size_t)255; return p;
  };
  unsigned short* xh = (unsigned short*)alloc((size_t)N_TOK * DIMS * 2);
  unsigned short* eh = (unsigned short*)alloc((size_t)KCB * DIMS * 2);
  float*    e2      = (float*)alloc(KCB * 4);
  double*   e2d     = (double*)alloc(KCB * 8);
  float*    counts  = (float*)alloc(KCB * 4);
  float*    esum    = (float*)alloc((size_t)KCB * DIMS * 4);   // contiguous after counts
  float*    pbest   = (float*)alloc((size_t)8 * N_TOK * 4);
  float*    psecond = (float*)alloc((size_t)8 * N_TOK * 4);
  float*    pthird  = (float*)alloc((size_t)8 * N_TOK * 4);
  uint32_t* pkk     = (uint32_t*)alloc((size_t)8 * N_TOK * 4);
  int*      ind     = (int*)alloc(N_TOK * 4);
  int*      candRows= (int*)alloc(N_TOK * 4);
  int*      candCnt = (int*)alloc(N_TOK * 4);
  int*      candIdx = (int*)alloc((size_t)N_TOK * 16 * 4);
  int*      listC   = (int*)alloc(N_TOK * 4);
  uint32_t* cntAB   = (uint32_t*)alloc(256);      // [0]=cand rows, [1]=listC
  double*   nsum    = (double*)alloc(256);
  int*      expired = (int*)alloc(KCB * 4);
  uint32_t* keys    = (uint32_t*)alloc(N_TOK * 4);
  uint32_t* valsA   = (uint32_t*)alloc(N_TOK * 4);
  uint32_t* bkey    = (uint32_t*)alloc(N_TOK * 4);
  uint32_t* bval    = (uint32_t*)alloc(N_TOK * 4);
  uint32_t* bpos    = (uint32_t*)alloc(N_TOK * 4);
  uint32_t* valsB   = (uint32_t*)alloc(N_TOK * 4);
  uint32_t* bcount  = (uint32_t*)alloc(KCB * 4);
  uint32_t* bbase   = (uint32_t*)alloc(KCB * 4);
  uint32_t* cursor  = (uint32_t*)alloc(KCB * 4);

  // zero accumulators (counts+esum contiguous), tie counters, bucket counts
  hipMemsetAsync(counts, 0, KCB * 4 + (size_t)KCB * DIMS * 4, stream);
  hipMemsetAsync(cntAB, 0, 256, stream);
  hipMemsetAsync(bcount, 0, KCB * 4, stream);

  e2_kernel<<<8, 256, 0, stream>>>(embed, e2, e2d);
  split_hi<<<6000, 256, 0, stream>>>(x, xh, N_TOK * DIMS / 8);
  split_hi<<<256, 256, 0, stream>>>(embed, eh, KCB * DIMS / 8);

  dist_mfma<<<3000, 256, 0, stream>>>(xh, eh, e2, pbest, psecond, pthird, pkk);
  merge8<<<188, 256, 0, stream>>>(pbest, psecond, pthird, pkk,
                                  ind, candRows, candIdx, candCnt, listC,
                                  &cntAB[0], &cntAB[1]);
  refine_cand<<<512, 256, 0, stream>>>(x, embed, e2d, candRows, candIdx, candCnt,
                                       &cntAB[0], ind);
  refine_fullC<<<1024, 256, 0, stream>>>(x, embed, e2d, listC, &cntAB[1], ind);

  gather_scatter<<<12000, 256, 0, stream>>>(x, embed, ind, outQ, outC, counts, esum);
  ema_stats<<<1, 1024, 0, stream>>>(cs, counts, outNCS, expired, nsum);

  // permutation: round 1 (vals = iota)
  keys_round<<<188, 256, 0, stream>>>(1, keys, valsA, bcount);
  scan2048<<<1, 1024, 0, stream>>>(bcount, bbase, cursor);
  scatter_buckets<<<188, 256, 0, stream>>>(keys, valsA, bbase, cursor, bkey, bval, bpos);
  rank_buckets<<<2048, 64, 0, stream>>>(bkey, bval, bpos, bbase, bcount, valsB);
  // round 2 (vals = round-1 output)
  hipMemsetAsync(bcount, 0, KCB * 4, stream);
  keys_round<<<188, 256, 0, stream>>>(2, keys, nullptr, bcount);
  scan2048<<<1, 1024, 0, stream>>>(bcount, bbase, cursor);
  scatter_buckets<<<188, 256, 0, stream>>>(keys, valsB, bbase, cursor, bkey, bval, bpos);
  rank_buckets<<<2048, 64, 0, stream>>>(bkey, bval, bpos, bbase, bcount, valsA);

  final_embed<<<512, 256, 0, stream>>>(x, cs, counts, eavg, esum, expired, nsum,
                                       valsA, outEAVG, outNE);
}

// Round 11
// 419.671 us; speedup vs baseline: 3.9484x; 1.2577x over previous
//
#include <hip/hip_runtime.h>
#include <hip/hip_bf16.h>
#include <stdint.h>
#include <math.h>

// Problem constants
#define N_TOK 48000     // 32*1500
#define DIMS  256
#define KCB   2048
// 1-pass bf16 approx score error: diff std ~6e-3, sub-Gaussian. Packed-u32
// quantization (11 dropped mantissa bits at |score|<32) adds <=0.008/side.
// WND = 0.10 >= 2*delta + 2*quant with >25% margin. True winner's packed
// score >= best - WND. Candidates = per-tile top-2; if a tile's THIRD value
// is in-window the winner may be unstored -> full f64 re-scan for that row.
#define WND 0.10f

typedef __attribute__((ext_vector_type(8))) short bf16x8;
typedef __attribute__((ext_vector_type(4))) float f32x4;
typedef __attribute__((ext_vector_type(8))) unsigned short u16x8;

// ---------------- bf16 helpers (explicit RNE) ----------------
__device__ __forceinline__ unsigned short bf16rn(float f) {
  uint32_t u = __float_as_uint(f);
  uint32_t r = (u + 0x7FFFu + ((u >> 16) & 1u)) >> 16;
  return (unsigned short)r;
}

// ---------------- packed sortable score: high21=monotone f32, low11=2047-k ----------------
__device__ __forceinline__ uint32_t packScore(float f, uint32_t invIdx) {
  uint32_t b = __float_as_uint(f);
  uint32_t m = (uint32_t)((int32_t)b >> 31) | 0x80000000u;
  return ((b ^ m) & ~0x7FFu) | invIdx;
}
__device__ __forceinline__ uint32_t packThr(float f) {
  uint32_t b = __float_as_uint(f);
  uint32_t m = (uint32_t)((int32_t)b >> 31) | 0x80000000u;
  return (b ^ m) & ~0x7FFu;
}
__device__ __forceinline__ float unpackScore(uint32_t u) {
  uint32_t v = u & ~0x7FFu;
  uint32_t b = (v & 0x80000000u) ? (v ^ 0x80000000u) : ~v;
  return __uint_as_float(b);
}
// branch-free sorted top-3 insert (b>=s>=t), 5 u32 min/max ops
__device__ __forceinline__ void ins3u(uint32_t& b, uint32_t& s, uint32_t& t, uint32_t v) {
  uint32_t lo = min(b, v);
  b = max(b, v);
  uint32_t lo2 = min(s, lo);
  s = max(s, lo);
  t = max(t, lo2);
}

// ---------------- Threefry-2x32 (matches jax._src.prng, partitionable) ----------------
__device__ inline void tf2x32(uint32_t k0, uint32_t k1, uint32_t c0, uint32_t c1,
                              uint32_t& o0, uint32_t& o1) {
  uint32_t ks2 = k0 ^ k1 ^ 0x1BD11BDAu;
  uint32_t x0 = c0 + k0, x1 = c1 + k1;
#define TF_R(r) { x0 += x1; x1 = (x1 << (r)) | (x1 >> (32 - (r))); x1 ^= x0; }
  TF_R(13) TF_R(15) TF_R(26) TF_R(6)
  x0 += k1; x1 += ks2 + 1u;
  TF_R(17) TF_R(29) TF_R(16) TF_R(24)
  x0 += ks2; x1 += k0 + 2u;
  TF_R(13) TF_R(15) TF_R(26) TF_R(6)
  x0 += k0; x1 += k1 + 3u;
  TF_R(17) TF_R(29) TF_R(16) TF_R(24)
  x0 += k1; x1 += ks2 + 4u;
  TF_R(13) TF_R(15) TF_R(26) TF_R(6)
  x0 += ks2; x1 += k0 + 5u;
#undef TF_R
  o0 = x0; o1 = x1;
}

__device__ inline void get_round_key(int round, uint32_t& ka, uint32_t& kb) {
  const uint32_t b0 = 0u, b1 = 1u;  // jax.random.key(1) -> (0,1)
  uint32_t K1a, K1b, S1a, S1b;
  tf2x32(b0, b1, 0u, 0u, K1a, K1b);
  tf2x32(b0, b1, 0u, 1u, S1a, S1b);
  if (round == 1) { ka = S1a; kb = S1b; return; }
  uint32_t S2a, S2b;
  tf2x32(K1a, K1b, 0u, 1u, S2a, S2b);
  ka = S2a; kb = S2b;
}

__device__ inline uint32_t gen_key(int round, uint32_t i) {
  uint32_t ka, kb, o0, o1;
  get_round_key(round, ka, kb);
  tf2x32(ka, kb, 0u, i, o0, o1);
  return o0 ^ o1;
}

// ---------------- global_load_lds wrapper (16B) ----------------
__device__ __forceinline__ void gload_lds16(const void* g, void* l) {
  __builtin_amdgcn_global_load_lds(
      (const __attribute__((address_space(1))) uint32_t*)g,
      (__attribute__((address_space(3))) uint32_t*)l, 16, 0, 0);
}

// ---------------- e2[k] = sum(embed[k]^2), f32 + f64 ----------------
__global__ void e2_kernel(const float* __restrict__ embed, float* __restrict__ e2,
                          double* __restrict__ e2d) {
  int k = blockIdx.x * blockDim.x + threadIdx.x;
  if (k >= KCB) return;
  const float4* er = (const float4*)(embed + (size_t)k * DIMS);
  float s = 0.f;
  double sd = 0.0;
  for (int c = 0; c < DIMS / 4; ++c) {
    float4 v = er[c];
    s = fmaf(v.x, v.x, s); s = fmaf(v.y, v.y, s);
    s = fmaf(v.z, v.z, s); s = fmaf(v.w, v.w, s);
    sd += (double)v.x * v.x + (double)v.y * v.y
        + (double)v.z * v.z + (double)v.w * v.w;
  }
  e2[k] = s;
  e2d[k] = sd;
}

// ---------------- f32 -> bf16 (RNE), x and embed in one launch ----------------
__global__ void split_both(const float* __restrict__ x, unsigned short* __restrict__ xh,
                           const float* __restrict__ embed, unsigned short* __restrict__ eh) {
  const int nx = N_TOK * DIMS / 8;
  const int ne = KCB * DIMS / 8;
  int i = blockIdx.x * blockDim.x + threadIdx.x;
  const float* src; unsigned short* dst; int j;
  if (i < nx) { src = x; dst = xh; j = i; }
  else if (i < nx + ne) { src = embed; dst = eh; j = i - nx; }
  else return;
  float4 a = ((const float4*)src)[j * 2];
  float4 b = ((const float4*)src)[j * 2 + 1];
  float v[8] = {a.x, a.y, a.z, a.w, b.x, b.y, b.z, b.w};
  u16x8 h;
#pragma unroll
  for (int q = 0; q < 8; ++q) h[q] = bf16rn(v[q]);
  *(u16x8*)&dst[(size_t)j * 8] = h;
}

// ---------------- MFMA distance top-3 (single bf16 pass, packed epilogue) ----------------
// approx score = 2*(xh.eh) - e2[k]; 128x256 tile, BK=32, 8 steps,
// double-buffered LDS. Bank swizzle (both-sides involution, rule 21):
// 64B rows = 4 chunks of 16B; physical chunk = logical ^ ((row>>1)&3).
// Epilogue: scores packed to sortable u32 (value high 21 | inv-index low 11),
// branch-free top-3 insert, cross-lane reduce via LDS table (NO shuffles).
__global__ __launch_bounds__(256, 2) void dist_mfma(
    const unsigned short* __restrict__ xh, const unsigned short* __restrict__ eh,
    const float* __restrict__ e2,
    uint32_t* __restrict__ pb, uint32_t* __restrict__ ps, uint32_t* __restrict__ pt)
{
  // staging (49152 B) and reduction table (128*98*4 = 50176 B) alias
  __shared__ __align__(16) char smem[50176];
  short (*As)[128 * 32] = (short(*)[128 * 32])smem;            // 2 x 8 KB
  short (*Bs)[256 * 32] = (short(*)[256 * 32])(smem + 16384);  // 2 x 16 KB
  uint32_t* red = (uint32_t*)smem;                             // [128][98] u32

  const int tid = threadIdx.x;
  const int lane = tid & 63, w = tid >> 6;
  const int wr = w >> 1, wc = w & 1;      // wave tile: 64 rows x 128 cols
  const int l15 = lane & 15, lg = lane >> 4;

  // XCD grouping: the 8 y-tiles sharing an x-tile get bids == same (mod 8),
  // spaced 8 apart -> same XCD L2 -> x-tile fetched from HBM once per XCD.
  int bx, by;
  {
    const int bid = blockIdx.x;
    if (bid < 2944) { int g = bid >> 6, r = bid & 63; bx = g * 8 + (r & 7); by = r >> 3; }
    else            { int t2 = bid - 2944; bx = 368 + (t2 % 7); by = t2 / 7; }
  }
  const int n0 = bx * 128;   // token tile base
  const int c0 = by * 256;   // code tile base

  f32x4 acc[4][8];
#pragma unroll
  for (int mf = 0; mf < 4; ++mf)
#pragma unroll
    for (int nf = 0; nf < 8; ++nf) acc[mf][nf] = (f32x4){0.f, 0.f, 0.f, 0.f};

  // stage step t into buffer t&1 (linear LDS dest; source pre-swizzled)
  auto stage = [&](int t) {
    const int d0 = t << 5;     // d-chunk of 32 shorts
    const int q = t & 1;
#pragma unroll
    for (int i = 0; i < 2; ++i) {
      const int c = i * 256 + tid;
      const int row = c >> 2;
      const int sc = ((c & 3) ^ ((row >> 1) & 3)) << 3;   // swizzled source chunk
      gload_lds16(xh + (size_t)(n0 + row) * DIMS + d0 + sc, (void*)&As[q][c * 8]);
    }
#pragma unroll
    for (int i = 0; i < 4; ++i) {
      const int c = i * 256 + tid;
      const int row = c >> 2;
      const int sc = ((c & 3) ^ ((row >> 1) & 3)) << 3;
      gload_lds16(eh + (size_t)(c0 + row) * DIMS + d0 + sc, (void*)&Bs[q][c * 8]);
    }
  };

  stage(0);
  __syncthreads();   // buf0 ready

#pragma unroll 1
  for (int t = 0; t < 8; ++t) {
    if (t < 7) stage(t + 1);         // issue next-step loads (overlap w/ compute)
    const int q = t & 1;
    bf16x8 af[4], bfv[8];
#pragma unroll
    for (int mf = 0; mf < 4; ++mf) {
      const int r = wr * 64 + mf * 16 + l15;
      af[mf] = *(const bf16x8*)&As[q][r * 32 + ((lg ^ ((r >> 1) & 3)) << 3)];
    }
#pragma unroll
    for (int nf = 0; nf < 8; ++nf) {
      const int r = wc * 128 + nf * 16 + l15;
      bfv[nf] = *(const bf16x8*)&Bs[q][r * 32 + ((lg ^ ((r >> 1) & 3)) << 3)];
    }
#pragma unroll
    for (int mf = 0; mf < 4; ++mf)
#pragma unroll
      for (int nf = 0; nf < 8; ++nf)
        acc[mf][nf] = __builtin_amdgcn_mfma_f32_16x16x32_bf16(
            af[mf], bfv[nf], acc[mf][nf], 0, 0, 0);
    __syncthreads();                 // staged loads drained + rw hazards
  }
  // K-loop done; last barrier above makes staging LDS safe to reuse as `red`.

  float e2v[8];
  uint32_t inv[8];
#pragma unroll
  for (int nf = 0; nf < 8; ++nf) {
    int k = c0 + wc * 128 + nf * 16 + l15;
    e2v[nf] = e2[k];
    inv[nf] = 2047u - (uint32_t)k;
  }

  const int colbase = wc * 16 + l15;
#pragma unroll
  for (int mf = 0; mf < 4; ++mf) {
#pragma unroll
    for (int reg = 0; reg < 4; ++reg) {
      uint32_t b = 0u, s = 0u, t3 = 0u;
#pragma unroll
      for (int nf = 0; nf < 8; ++nf) {
        float f = fmaf(2.f, acc[mf][nf][reg], -e2v[nf]);
        ins3u(b, s, t3, packScore(f, inv[nf]));
      }
      const int row = wr * 64 + mf * 16 + lg * 4 + reg;
      uint32_t* p = &red[row * 98 + colbase * 3];
      p[0] = b; p[1] = s; p[2] = t3;
    }
  }
  __syncthreads();
  if (tid < 128) {
    uint32_t b = 0u, s = 0u, t3 = 0u;
    const uint32_t* p = &red[tid * 98];
#pragma unroll 4
    for (int c = 0; c < 32; ++c) {
      ins3u(b, s, t3, p[c * 3 + 0]);
      ins3u(b, s, t3, p[c * 3 + 1]);
      ins3u(b, s, t3, p[c * 3 + 2]);
    }
    size_t o = (size_t)by * N_TOK + n0 + tid;
    pb[o] = b; ps[o] = s; pt[o] = t3;
  }
}

// ---------------- merge 8 column-tile partials + candidate collection ----------------
__global__ void merge8(const uint32_t* __restrict__ pb, const uint32_t* __restrict__ ps,
                       const uint32_t* __restrict__ pt,
                       int* __restrict__ ind,
                       int* __restrict__ candRows, int* __restrict__ candIdx,
                       int* __restrict__ candCnt, int* __restrict__ listC,
                       uint32_t* __restrict__ cntA, uint32_t* __restrict__ cntC) {
  int n = blockIdx.x * blockDim.x + threadIdx.x;
  if (n >= N_TOK) return;
  uint32_t tb[8], tsv[8], ttv[8];
#pragma unroll
  for (int tt = 0; tt < 8; ++tt) {
    size_t o = (size_t)tt * N_TOK + n;
    tb[tt] = pb[o]; tsv[tt] = ps[o]; ttv[tt] = pt[o];
  }
  uint32_t best = tb[0];
#pragma unroll
  for (int tt = 1; tt < 8; ++tt) best = max(best, tb[tt]);
  ind[n] = 2047 - (int)(best & 0x7FFu);   // provisional winner
  const uint32_t thr = packThr(unpackScore(best) - WND);
  int m = 0; bool full = false;
#pragma unroll
  for (int tt = 0; tt < 8; ++tt) {
    m += (tb[tt] >= thr) + (tsv[tt] >= thr);
    full = full || (ttv[tt] >= thr);   // a tile's unstored 3rd+ could be in-window
  }
  if (full) {
    listC[atomicAdd(cntC, 1u)] = n;
  } else if (m > 1) {
    uint32_t i = atomicAdd(cntA, 1u);
    candRows[i] = n; candCnt[i] = m;
    int j = 0;
#pragma unroll
    for (int tt = 0; tt < 8; ++tt) {
      if (tb[tt]  >= thr) candIdx[(size_t)i * 16 + (j++)] = 2047 - (int)(tb[tt]  & 0x7FFu);
      if (tsv[tt] >= thr) candIdx[(size_t)i * 16 + (j++)] = 2047 - (int)(tsv[tt] & 0x7FFu);
    }
  }
}

// ---------------- wave-per-row f64 candidate decider ----------------
__global__ void refine_cand(const float* __restrict__ x, const float* __restrict__ embed,
                            const double* __restrict__ e2d,
                            const int* __restrict__ candRows, const int* __restrict__ candIdx,
                            const int* __restrict__ candCnt, const uint32_t* __restrict__ cntA,
                            int* __restrict__ ind) {
  const uint32_t nA = cntA[0];
  const int lane = threadIdx.x & 63;
  const uint32_t wid = (blockIdx.x * blockDim.x + threadIdx.x) >> 6;
  const uint32_t nw = (gridDim.x * blockDim.x) >> 6;
  for (uint32_t i = wid; i < nA; i += nw) {
    const int n = candRows[i];
    const int m = candCnt[i];
    float4 xv = ((const float4*)x)[(size_t)n * 64 + lane];
    double best = -1e300; int bk = 0x7fffffff;
    for (int j = 0; j < m; ++j) {
      int k = candIdx[(size_t)i * 16 + j];
      float4 e4 = ((const float4*)embed)[(size_t)k * 64 + lane];
      double d = (double)xv.x * e4.x + (double)xv.y * e4.y
               + (double)xv.z * e4.z + (double)xv.w * e4.w;
#pragma unroll
      for (int mm = 1; mm < 64; mm <<= 1) d += __shfl_xor(d, mm);
      double v = 2.0 * d - e2d[k];
      if (v > best || (v == best && k < bk)) { best = v; bk = k; }
    }
    if (lane == 0) ind[n] = bk;
  }
}

// ---------------- full f64 re-scan, one row per block (rare) ----------------
__global__ void refine_fullC(const float* __restrict__ x, const float* __restrict__ embed,
                             const double* __restrict__ e2d,
                             const int* __restrict__ listC, const uint32_t* __restrict__ cntC,
                             int* __restrict__ ind) {
  __shared__ double xd[DIMS];
  __shared__ double rv[256];
  __shared__ int    rk[256];
  const int tid = threadIdx.x;
  const uint32_t nC = cntC[0];
  for (uint32_t it = blockIdx.x; it < nC; it += gridDim.x) {
    const int n = listC[it];
    __syncthreads();
    xd[tid] = (double)x[(size_t)n * DIMS + tid];
    __syncthreads();
    double best = -1e300; int bk = 0x7fffffff;
    for (int k = tid; k < KCB; k += 256) {
      const float4* er = (const float4*)(embed + (size_t)k * DIMS);
      double a0 = 0.0, a1 = 0.0, a2 = 0.0, a3 = 0.0;   // ILP-4 chains
      for (int c = 0; c < 64; c += 4) {
        float4 ea = er[c], eb = er[c + 1], ec = er[c + 2], ed = er[c + 3];
        int d = c * 4;
        a0 += xd[d + 0] * ea.x + xd[d + 1] * ea.y + xd[d + 2] * ea.z + xd[d + 3] * ea.w;
        a1 += xd[d + 4] * eb.x + xd[d + 5] * eb.y + xd[d + 6] * eb.z + xd[d + 7] * eb.w;
        a2 += xd[d + 8] * ec.x + xd[d + 9] * ec.y + xd[d + 10] * ec.z + xd[d + 11] * ec.w;
        a3 += xd[d + 12] * ed.x + xd[d + 13] * ed.y + xd[d + 14] * ed.z + xd[d + 15] * ed.w;
      }
      double v = 2.0 * (a0 + a1 + a2 + a3) - e2d[k];
      if (v > best || (v == best && k < bk)) { best = v; bk = k; }
    }
    rv[tid] = best; rk[tid] = bk;
    __syncthreads();
    for (int s = 128; s > 0; s >>= 1) {
      if (tid < s) {
        double v2 = rv[tid + s]; int k2 = rk[tid + s];
        if (v2 > rv[tid] || (v2 == rv[tid] && k2 < rk[tid])) { rv[tid] = v2; rk[tid] = k2; }
      }
      __syncthreads();
    }
    if (tid == 0) ind[n] = rk[0];
  }
}

// ---------------- quantize gather + codes + counts + embed_sum ----------------
__global__ void gather_scatter(const float* __restrict__ x, const float* __restrict__ embed,
                               const int* __restrict__ ind,
                               float* __restrict__ outq, float* __restrict__ outcodes,
                               float* __restrict__ counts, float* __restrict__ esum) {
  int idx = blockIdx.x * blockDim.x + threadIdx.x;   // over N_TOK*64 float4s
  if (idx >= N_TOK * 64) return;
  int n = idx >> 6, c = idx & 63;
  int k = ind[n];
  float4 e = ((const float4*)embed)[(size_t)k * 64 + c];
  ((float4*)outq)[idx] = e;
  float4 xv = ((const float4*)x)[idx];
  float* base = esum + (size_t)k * DIMS + c * 4;
  atomicAdd(base + 0, xv.x); atomicAdd(base + 1, xv.y);
  atomicAdd(base + 2, xv.z); atomicAdd(base + 3, xv.w);
  if (c == 0) { outcodes[n] = (float)k; atomicAdd(&counts[k], 1.0f); }
}

// ---------------- new_cluster_size + n-sum + expired ----------------
__global__ void ema_stats(const float* __restrict__ cs, const float* __restrict__ counts,
                          float* __restrict__ out_ncs, int* __restrict__ expired,
                          double* __restrict__ nsum) {
  __shared__ double sd[1024];
  int tid = threadIdx.x;
  double local = 0.0;
  for (int k = tid; k < KCB; k += 1024) {
    double v = 0.99 * (double)cs[k] + 0.01 * (double)counts[k];
    out_ncs[k] = (float)v;
    expired[k] = (v < 2.0) ? 1 : 0;
    local += v;
  }
  sd[tid] = local; __syncthreads();
  for (int s = 512; s > 0; s >>= 1) { if (tid < s) sd[tid] += sd[tid + s]; __syncthreads(); }
  if (tid == 0) nsum[0] = sd[0];
}

// ---------------- new_embed_avg + new_embed ----------------
__global__ void final_embed(const float* __restrict__ x, const float* __restrict__ cs,
                            const float* __restrict__ counts,
                            const float* __restrict__ eavg, const float* __restrict__ esum,
                            const int* __restrict__ expired, const double* __restrict__ nsum,
                            const uint32_t* __restrict__ perm,
                            float* __restrict__ out_eavg, float* __restrict__ out_ne) {
  int idx = blockIdx.x * blockDim.x + threadIdx.x;   // over KCB*64 float4s
  if (idx >= KCB * 64) return;
  int k = idx >> 6, c = idx & 63;
  float4 ea = ((const float4*)eavg)[idx];
  float4 es = ((const float4*)esum)[idx];
  double ax = 0.99 * (double)ea.x + 0.01 * (double)es.x;
  double ay = 0.99 * (double)ea.y + 0.01 * (double)es.y;
  double az = 0.99 * (double)ea.z + 0.01 * (double)es.z;
  double aw = 0.99 * (double)ea.w + 0.01 * (double)es.w;
  float4 nv; nv.x = (float)ax; nv.y = (float)ay; nv.z = (float)az; nv.w = (float)aw;
  ((float4*)out_eavg)[idx] = nv;
  float4 r;
  if (expired[k]) {
    r = ((const float4*)x)[(size_t)perm[k] * 64 + c];
  } else {
    double ncs = 0.99 * (double)cs[k] + 0.01 * (double)counts[k];
    double n = nsum[0];
    double sm = (ncs + 1e-5) / (n + 2048.0 * 1e-5) * n;
    r.x = (float)(ax / sm); r.y = (float)(ay / sm);
    r.z = (float)(az / sm); r.w = (float)(aw / sm);
  }
  ((float4*)out_ne)[idx] = r;
}

// ---------------- permutation pipeline (stable sort by random keys) ----------------
__global__ void keys_round(int round, uint32_t* __restrict__ keys,
                           uint32_t* __restrict__ vals_init, uint32_t* __restrict__ bcount) {
  int i = blockIdx.x * blockDim.x + threadIdx.x;
  if (i >= N_TOK) return;
  uint32_t key = gen_key(round, (uint32_t)i);
  keys[i] = key;
  if (vals_init) vals_init[i] = (uint32_t)i;
  atomicAdd(&bcount[key >> 21], 1u);
}

__global__ void scan2048(const uint32_t* __restrict__ in, uint32_t* __restrict__ out,
                         uint32_t* __restrict__ cursor_zero) {
  __shared__ uint32_t buf[2][2048];
  int t = threadIdx.x;   // 1024
  for (int q = 0; q < 2; ++q) buf[0][t + q * 1024] = in[t + q * 1024];
  cursor_zero[t] = 0; cursor_zero[t + 1024] = 0;
  __syncthreads();
  int src = 0;
  for (int off = 1; off < 2048; off <<= 1) {
    for (int q = 0; q < 2; ++q) {
      int i = t + q * 1024;
      uint32_t v = buf[src][i];
      if (i >= off) v += buf[src][i - off];
      buf[src ^ 1][i] = v;
    }
    src ^= 1; __syncthreads();
  }
  for (int q = 0; q < 2; ++q) {
    int i = t + q * 1024;
    out[i] = buf[src][i] - in[i];   // exclusive
  }
}

__global__ void scatter_buckets(const uint32_t* __restrict__ keys, const uint32_t* __restrict__ vals_in,
                                const uint32_t* __restrict__ bbase, uint32_t* __restrict__ cursor,
                                uint32_t* __restrict__ bkey, uint32_t* __restrict__ bval,
                                uint32_t* __restrict__ bpos) {
  int i = blockIdx.x * blockDim.x + threadIdx.x;
  if (i >= N_TOK) return;
  uint32_t k = keys[i];
  uint32_t b = k >> 21;
  uint32_t p = atomicAdd(&cursor[b], 1u);
  uint32_t s = bbase[b] + p;
  bkey[s] = k; bval[s] = vals_in[i]; bpos[s] = (uint32_t)i;
}

__global__ void rank_buckets(const uint32_t* __restrict__ bkey, const uint32_t* __restrict__ bval,
                             const uint32_t* __restrict__ bpos, const uint32_t* __restrict__ bbase,
                             const uint32_t* __restrict__ bcount, uint32_t* __restrict__ out_vals) {
  int b = blockIdx.x;
  uint32_t base = bbase[b], cnt = bcount[b];
  for (uint32_t t = threadIdx.x; t < cnt; t += blockDim.x) {
    uint32_t k = bkey[base + t], p = bpos[base + t];
    uint32_t r = 0;
    for (uint32_t j = 0; j < cnt; ++j) {
      uint32_t kj = bkey[base + j], pj = bpos[base + j];
      r += (kj < k) | ((kj == k) & (pj < p));
    }
    out_vals[base + r] = bval[base + t];
  }
}

// ---------------- launch ----------------
extern "C" void kernel_launch(void* const* d_in, const int* in_sizes, int n_in,
                              void* d_out, int out_size, void* d_ws, size_t ws_size,
                              hipStream_t stream) {
  const float* x     = (const float*)d_in[0];
  const float* embed = (const float*)d_in[1];
  const float* cs    = (const float*)d_in[2];
  const float* eavg  = (const float*)d_in[3];

  float* out = (float*)d_out;
  float* outQ    = out;                  // 12,288,000
  float* outC    = out + 12288000;       // 48,000
  float* outNCS  = out + 12336000;       // 2,048
  float* outEAVG = out + 12338048;       // 524,288
  float* outNE   = out + 12862336;       // 524,288

  char* w = (char*)d_ws;
  size_t off = 0;
  auto alloc = [&](size_t bytes) -> void* {
    void* p = w + off; off += (bytes + 255) & ~(size_t)255; return p;
  };
  unsigned short* xh = (unsigned short*)alloc((size_t)N_TOK * DIMS * 2);
  unsigned short* eh = (unsigned short*)alloc((size_t)KCB * DIMS * 2);
  float*    e2      = (float*)alloc(KCB * 4);
  double*   e2d     = (double*)alloc(KCB * 8);
  float*    counts  = (float*)alloc(KCB * 4);
  float*    esum    = (float*)alloc((size_t)KCB * DIMS * 4);   // contiguous after counts
  uint32_t* pbest   = (uint32_t*)alloc((size_t)8 * N_TOK * 4);
  uint32_t* psecond = (uint32_t*)alloc((size_t)8 * N_TOK * 4);
  uint32_t* pthird  = (uint32_t*)alloc((size_t)8 * N_TOK * 4);
  int*      ind     = (int*)alloc(N_TOK * 4);
  int*      candRows= (int*)alloc(N_TOK * 4);
  int*      candCnt = (int*)alloc(N_TOK * 4);
  int*      candIdx = (int*)alloc((size_t)N_TOK * 16 * 4);
  int*      listC   = (int*)alloc(N_TOK * 4);
  uint32_t* cntAB   = (uint32_t*)alloc(256);      // [0]=cand rows, [1]=listC
  double*   nsum    = (double*)alloc(256);
  int*      expired = (int*)alloc(KCB * 4);
  uint32_t* keys    = (uint32_t*)alloc(N_TOK * 4);
  uint32_t* valsA   = (uint32_t*)alloc(N_TOK * 4);
  uint32_t* bkey    = (uint32_t*)alloc(N_TOK * 4);
  uint32_t* bval    = (uint32_t*)alloc(N_TOK * 4);
  uint32_t* bpos    = (uint32_t*)alloc(N_TOK * 4);
  uint32_t* valsB   = (uint32_t*)alloc(N_TOK * 4);
  uint32_t* bcount  = (uint32_t*)alloc(KCB * 4);
  uint32_t* bbase   = (uint32_t*)alloc(KCB * 4);
  uint32_t* cursor  = (uint32_t*)alloc(KCB * 4);

  // zero accumulators (counts+esum contiguous), tie counters, bucket counts
  hipMemsetAsync(counts, 0, KCB * 4 + (size_t)KCB * DIMS * 4, stream);
  hipMemsetAsync(cntAB, 0, 256, stream);
  hipMemsetAsync(bcount, 0, KCB * 4, stream);

  e2_kernel<<<8, 256, 0, stream>>>(embed, e2, e2d);
  split_both<<<(N_TOK * DIMS / 8 + KCB * DIMS / 8 + 255) / 256, 256, 0, stream>>>(
      x, xh, embed, eh);

  dist_mfma<<<3000, 256, 0, stream>>>(xh, eh, e2, pbest, psecond, pthird);
  merge8<<<188, 256, 0, stream>>>(pbest, psecond, pthird,
                                  ind, candRows, candIdx, candCnt, listC,
                                  &cntAB[0], &cntAB[1]);
  refine_cand<<<512, 256, 0, stream>>>(x, embed, e2d, candRows, candIdx, candCnt,
                                       &cntAB[0], ind);
  refine_fullC<<<1024, 256, 0, stream>>>(x, embed, e2d, listC, &cntAB[1], ind);

  gather_scatter<<<12000, 256, 0, stream>>>(x, embed, ind, outQ, outC, counts, esum);
  ema_stats<<<1, 1024, 0, stream>>>(cs, counts, outNCS, expired, nsum);

  // permutation: round 1 (vals = iota)
  keys_round<<<188, 256, 0, stream>>>(1, keys, valsA, bcount);
  scan2048<<<1, 1024, 0, stream>>>(bcount, bbase, cursor);
  scatter_buckets<<<188, 256, 0, stream>>>(keys, valsA, bbase, cursor, bkey, bval, bpos);
  rank_buckets<<<2048, 64, 0, stream>>>(bkey, bval, bpos, bbase, bcount, valsB);
  // round 2 (vals = round-1 output)
  hipMemsetAsync(bcount, 0, KCB * 4, stream);
  keys_round<<<188, 256, 0, stream>>>(2, keys, nullptr, bcount);
  scan2048<<<1, 1024, 0, stream>>>(bcount, bbase, cursor);
  scatter_buckets<<<188, 256, 0, stream>>>(keys, valsB, bbase, cursor, bkey, bval, bpos);
  rank_buckets<<<2048, 64, 0, stream>>>(bkey, bval, bpos, bbase, bcount, valsA);

  final_embed<<<512, 256, 0, stream>>>(x, cs, counts, eavg, esum, expired, nsum,
                                       valsA, outEAVG, outNE);
}

// Round 12
// 284.074 us; speedup vs baseline: 5.8331x; 1.4773x over previous
//
#include <hip/hip_runtime.h>
#include <hip/hip_bf16.h>
#include <stdint.h>
#include <math.h>

// Problem constants
#define N_TOK 48000     // 32*1500
#define DIMS  256
#define KCB   2048
// 1-pass bf16 approx score error: diff std ~6e-3, sub-Gaussian. Packed-u32
// quantization (11 dropped mantissa bits at |score|<32) adds <=0.008/side.
// WND = 0.10 >= 2*delta + 2*quant with >25% margin. True winner's packed
// score >= best - WND. Candidates = per-tile top-2; if a tile's THIRD value
// is in-window the winner may be unstored -> full f64 re-scan for that row.
#define WND 0.10f

typedef __attribute__((ext_vector_type(8))) short bf16x8;
typedef __attribute__((ext_vector_type(4))) float f32x4;
typedef __attribute__((ext_vector_type(8))) unsigned short u16x8;

// ---------------- bf16 helpers (explicit RNE) ----------------
__device__ __forceinline__ unsigned short bf16rn(float f) {
  uint32_t u = __float_as_uint(f);
  uint32_t r = (u + 0x7FFFu + ((u >> 16) & 1u)) >> 16;
  return (unsigned short)r;
}

// ---------------- packed sortable score: high21=monotone f32, low11=2047-k ----------------
__device__ __forceinline__ uint32_t packScore(float f, uint32_t invIdx) {
  uint32_t b = __float_as_uint(f);
  uint32_t m = (uint32_t)((int32_t)b >> 31) | 0x80000000u;
  return ((b ^ m) & ~0x7FFu) | invIdx;
}
__device__ __forceinline__ uint32_t packThr(float f) {
  uint32_t b = __float_as_uint(f);
  uint32_t m = (uint32_t)((int32_t)b >> 31) | 0x80000000u;
  return (b ^ m) & ~0x7FFu;
}
__device__ __forceinline__ float unpackScore(uint32_t u) {
  uint32_t v = u & ~0x7FFu;
  uint32_t b = (v & 0x80000000u) ? (v ^ 0x80000000u) : ~v;
  return __uint_as_float(b);
}
// branch-free sorted top-3 insert (b>=s>=t), 5 u32 min/max ops
__device__ __forceinline__ void ins3u(uint32_t& b, uint32_t& s, uint32_t& t, uint32_t v) {
  uint32_t lo = min(b, v);
  b = max(b, v);
  uint32_t lo2 = min(s, lo);
  s = max(s, lo);
  t = max(t, lo2);
}

// ---------------- Threefry-2x32 (matches jax._src.prng, partitionable) ----------------
__device__ inline void tf2x32(uint32_t k0, uint32_t k1, uint32_t c0, uint32_t c1,
                              uint32_t& o0, uint32_t& o1) {
  uint32_t ks2 = k0 ^ k1 ^ 0x1BD11BDAu;
  uint32_t x0 = c0 + k0, x1 = c1 + k1;
#define TF_R(r) { x0 += x1; x1 = (x1 << (r)) | (x1 >> (32 - (r))); x1 ^= x0; }
  TF_R(13) TF_R(15) TF_R(26) TF_R(6)
  x0 += k1; x1 += ks2 + 1u;
  TF_R(17) TF_R(29) TF_R(16) TF_R(24)
  x0 += ks2; x1 += k0 + 2u;
  TF_R(13) TF_R(15) TF_R(26) TF_R(6)
  x0 += k0; x1 += k1 + 3u;
  TF_R(17) TF_R(29) TF_R(16) TF_R(24)
  x0 += k1; x1 += ks2 + 4u;
  TF_R(13) TF_R(15) TF_R(26) TF_R(6)
  x0 += ks2; x1 += k0 + 5u;
#undef TF_R
  o0 = x0; o1 = x1;
}

__device__ inline void get_round_key(int round, uint32_t& ka, uint32_t& kb) {
  const uint32_t b0 = 0u, b1 = 1u;  // jax.random.key(1) -> (0,1)
  uint32_t K1a, K1b, S1a, S1b;
  tf2x32(b0, b1, 0u, 0u, K1a, K1b);
  tf2x32(b0, b1, 0u, 1u, S1a, S1b);
  if (round == 1) { ka = S1a; kb = S1b; return; }
  uint32_t S2a, S2b;
  tf2x32(K1a, K1b, 0u, 1u, S2a, S2b);
  ka = S2a; kb = S2b;
}

__device__ inline uint32_t gen_key(int round, uint32_t i) {
  uint32_t ka, kb, o0, o1;
  get_round_key(round, ka, kb);
  tf2x32(ka, kb, 0u, i, o0, o1);
  return o0 ^ o1;
}

// ---------------- global_load_lds wrapper (16B) ----------------
__device__ __forceinline__ void gload_lds16(const void* g, void* l) {
  __builtin_amdgcn_global_load_lds(
      (const __attribute__((address_space(1))) uint32_t*)g,
      (__attribute__((address_space(3))) uint32_t*)l, 16, 0, 0);
}

// ---------------- e2[k] = sum(embed[k]^2), f32 + f64 ----------------
__global__ void e2_kernel(const float* __restrict__ embed, float* __restrict__ e2,
                          double* __restrict__ e2d) {
  int k = blockIdx.x * blockDim.x + threadIdx.x;
  if (k >= KCB) return;
  const float4* er = (const float4*)(embed + (size_t)k * DIMS);
  float s = 0.f;
  double sd = 0.0;
  for (int c = 0; c < DIMS / 4; ++c) {
    float4 v = er[c];
    s = fmaf(v.x, v.x, s); s = fmaf(v.y, v.y, s);
    s = fmaf(v.z, v.z, s); s = fmaf(v.w, v.w, s);
    sd += (double)v.x * v.x + (double)v.y * v.y
        + (double)v.z * v.z + (double)v.w * v.w;
  }
  e2[k] = s;
  e2d[k] = sd;
}

// ---------------- f32 -> bf16 (RNE), x and embed in one launch ----------------
__global__ void split_both(const float* __restrict__ x, unsigned short* __restrict__ xh,
                           const float* __restrict__ embed, unsigned short* __restrict__ eh) {
  const int nx = N_TOK * DIMS / 8;
  const int ne = KCB * DIMS / 8;
  int i = blockIdx.x * blockDim.x + threadIdx.x;
  const float* src; unsigned short* dst; int j;
  if (i < nx) { src = x; dst = xh; j = i; }
  else if (i < nx + ne) { src = embed; dst = eh; j = i - nx; }
  else return;
  float4 a = ((const float4*)src)[j * 2];
  float4 b = ((const float4*)src)[j * 2 + 1];
  float v[8] = {a.x, a.y, a.z, a.w, b.x, b.y, b.z, b.w};
  u16x8 h;
#pragma unroll
  for (int q = 0; q < 8; ++q) h[q] = bf16rn(v[q]);
  *(u16x8*)&dst[(size_t)j * 8] = h;
}

// ---------------- MFMA distance top-3 (single bf16 pass, packed epilogue) ----------------
// approx score = 2*(xh.eh) - e2[k]; 128x256 tile, BK=32, 8 steps,
// double-buffered LDS. Bank swizzle (both-sides involution, rule 21):
// 64B rows = 4 chunks of 16B; physical chunk = logical ^ ((row>>1)&3).
// Epilogue: scores packed to sortable u32 (value high 21 | inv-index low 11),
// branch-free top-3 insert, cross-lane reduce via LDS table (NO shuffles).
__global__ __launch_bounds__(256, 2) void dist_mfma(
    const unsigned short* __restrict__ xh, const unsigned short* __restrict__ eh,
    const float* __restrict__ e2,
    uint32_t* __restrict__ pb, uint32_t* __restrict__ ps, uint32_t* __restrict__ pt)
{
  // staging (49152 B) and reduction table (128*98*4 = 50176 B) alias
  __shared__ __align__(16) char smem[50176];
  short (*As)[128 * 32] = (short(*)[128 * 32])smem;            // 2 x 8 KB
  short (*Bs)[256 * 32] = (short(*)[256 * 32])(smem + 16384);  // 2 x 16 KB
  uint32_t* red = (uint32_t*)smem;                             // [128][98] u32

  const int tid = threadIdx.x;
  const int lane = tid & 63, w = tid >> 6;
  const int wr = w >> 1, wc = w & 1;      // wave tile: 64 rows x 128 cols
  const int l15 = lane & 15, lg = lane >> 4;

  // XCD grouping: the 8 y-tiles sharing an x-tile get bids == same (mod 8),
  // spaced 8 apart -> same XCD L2 -> x-tile fetched from HBM once per XCD.
  int bx, by;
  {
    const int bid = blockIdx.x;
    if (bid < 2944) { int g = bid >> 6, r = bid & 63; bx = g * 8 + (r & 7); by = r >> 3; }
    else            { int t2 = bid - 2944; bx = 368 + (t2 % 7); by = t2 / 7; }
  }
  const int n0 = bx * 128;   // token tile base
  const int c0 = by * 256;   // code tile base

  f32x4 acc[4][8];
#pragma unroll
  for (int mf = 0; mf < 4; ++mf)
#pragma unroll
    for (int nf = 0; nf < 8; ++nf) acc[mf][nf] = (f32x4){0.f, 0.f, 0.f, 0.f};

  // stage step t into buffer t&1 (linear LDS dest; source pre-swizzled)
  auto stage = [&](int t) {
    const int d0 = t << 5;     // d-chunk of 32 shorts
    const int q = t & 1;
#pragma unroll
    for (int i = 0; i < 2; ++i) {
      const int c = i * 256 + tid;
      const int row = c >> 2;
      const int sc = ((c & 3) ^ ((row >> 1) & 3)) << 3;   // swizzled source chunk
      gload_lds16(xh + (size_t)(n0 + row) * DIMS + d0 + sc, (void*)&As[q][c * 8]);
    }
#pragma unroll
    for (int i = 0; i < 4; ++i) {
      const int c = i * 256 + tid;
      const int row = c >> 2;
      const int sc = ((c & 3) ^ ((row >> 1) & 3)) << 3;
      gload_lds16(eh + (size_t)(c0 + row) * DIMS + d0 + sc, (void*)&Bs[q][c * 8]);
    }
  };

  stage(0);
  __syncthreads();   // buf0 ready

#pragma unroll 1
  for (int t = 0; t < 8; ++t) {
    if (t < 7) stage(t + 1);         // issue next-step loads (overlap w/ compute)
    const int q = t & 1;
    bf16x8 af[4], bfv[8];
#pragma unroll
    for (int mf = 0; mf < 4; ++mf) {
      const int r = wr * 64 + mf * 16 + l15;
      af[mf] = *(const bf16x8*)&As[q][r * 32 + ((lg ^ ((r >> 1) & 3)) << 3)];
    }
#pragma unroll
    for (int nf = 0; nf < 8; ++nf) {
      const int r = wc * 128 + nf * 16 + l15;
      bfv[nf] = *(const bf16x8*)&Bs[q][r * 32 + ((lg ^ ((r >> 1) & 3)) << 3)];
    }
#pragma unroll
    for (int mf = 0; mf < 4; ++mf)
#pragma unroll
      for (int nf = 0; nf < 8; ++nf)
        acc[mf][nf] = __builtin_amdgcn_mfma_f32_16x16x32_bf16(
            af[mf], bfv[nf], acc[mf][nf], 0, 0, 0);
    __syncthreads();                 // staged loads drained + rw hazards
  }
  // K-loop done; last barrier above makes staging LDS safe to reuse as `red`.

  float e2v[8];
  uint32_t inv[8];
#pragma unroll
  for (int nf = 0; nf < 8; ++nf) {
    int k = c0 + wc * 128 + nf * 16 + l15;
    e2v[nf] = e2[k];
    inv[nf] = 2047u - (uint32_t)k;
  }

  const int colbase = wc * 16 + l15;
#pragma unroll
  for (int mf = 0; mf < 4; ++mf) {
#pragma unroll
    for (int reg = 0; reg < 4; ++reg) {
      uint32_t b = 0u, s = 0u, t3 = 0u;
#pragma unroll
      for (int nf = 0; nf < 8; ++nf) {
        float f = fmaf(2.f, acc[mf][nf][reg], -e2v[nf]);
        ins3u(b, s, t3, packScore(f, inv[nf]));
      }
      const int row = wr * 64 + mf * 16 + lg * 4 + reg;
      uint32_t* p = &red[row * 98 + colbase * 3];
      p[0] = b; p[1] = s; p[2] = t3;
    }
  }
  __syncthreads();
  if (tid < 128) {
    uint32_t b = 0u, s = 0u, t3 = 0u;
    const uint32_t* p = &red[tid * 98];
#pragma unroll 4
    for (int c = 0; c < 32; ++c) {
      ins3u(b, s, t3, p[c * 3 + 0]);
      ins3u(b, s, t3, p[c * 3 + 1]);
      ins3u(b, s, t3, p[c * 3 + 2]);
    }
    size_t o = (size_t)by * N_TOK + n0 + tid;
    pb[o] = b; ps[o] = s; pt[o] = t3;
  }
}

// ---------------- merge 8 column-tile partials + candidate collection ----------------
__global__ void merge8(const uint32_t* __restrict__ pb, const uint32_t* __restrict__ ps,
                       const uint32_t* __restrict__ pt,
                       int* __restrict__ ind,
                       int* __restrict__ candRows, int* __restrict__ candIdx,
                       int* __restrict__ candCnt, int* __restrict__ listC,
                       uint32_t* __restrict__ cntA, uint32_t* __restrict__ cntC) {
  int n = blockIdx.x * blockDim.x + threadIdx.x;
  if (n >= N_TOK) return;
  uint32_t tb[8], tsv[8], ttv[8];
#pragma unroll
  for (int tt = 0; tt < 8; ++tt) {
    size_t o = (size_t)tt * N_TOK + n;
    tb[tt] = pb[o]; tsv[tt] = ps[o]; ttv[tt] = pt[o];
  }
  uint32_t best = tb[0];
#pragma unroll
  for (int tt = 1; tt < 8; ++tt) best = max(best, tb[tt]);
  ind[n] = 2047 - (int)(best & 0x7FFu);   // provisional winner
  const uint32_t thr = packThr(unpackScore(best) - WND);
  int m = 0; bool full = false;
#pragma unroll
  for (int tt = 0; tt < 8; ++tt) {
    m += (tb[tt] >= thr) + (tsv[tt] >= thr);
    full = full || (ttv[tt] >= thr);   // a tile's unstored 3rd+ could be in-window
  }
  if (full) {
    listC[atomicAdd(cntC, 1u)] = n;
  } else if (m > 1) {
    uint32_t i = atomicAdd(cntA, 1u);
    candRows[i] = n; candCnt[i] = m;
    int j = 0;
#pragma unroll
    for (int tt = 0; tt < 8; ++tt) {
      if (tb[tt]  >= thr) candIdx[(size_t)i * 16 + (j++)] = 2047 - (int)(tb[tt]  & 0x7FFu);
      if (tsv[tt] >= thr) candIdx[(size_t)i * 16 + (j++)] = 2047 - (int)(tsv[tt] & 0x7FFu);
    }
  }
}

// ---------------- wave-per-row f64 candidate decider ----------------
__global__ void refine_cand(const float* __restrict__ x, const float* __restrict__ embed,
                            const double* __restrict__ e2d,
                            const int* __restrict__ candRows, const int* __restrict__ candIdx,
                            const int* __restrict__ candCnt, const uint32_t* __restrict__ cntA,
                            int* __restrict__ ind) {
  const uint32_t nA = cntA[0];
  const int lane = threadIdx.x & 63;
  const uint32_t wid = (blockIdx.x * blockDim.x + threadIdx.x) >> 6;
  const uint32_t nw = (gridDim.x * blockDim.x) >> 6;
  for (uint32_t i = wid; i < nA; i += nw) {
    const int n = candRows[i];
    const int m = candCnt[i];
    float4 xv = ((const float4*)x)[(size_t)n * 64 + lane];
    double best = -1e300; int bk = 0x7fffffff;
    for (int j = 0; j < m; ++j) {
      int k = candIdx[(size_t)i * 16 + j];
      float4 e4 = ((const float4*)embed)[(size_t)k * 64 + lane];
      double d = (double)xv.x * e4.x + (double)xv.y * e4.y
               + (double)xv.z * e4.z + (double)xv.w * e4.w;
#pragma unroll
      for (int mm = 1; mm < 64; mm <<= 1) d += __shfl_xor(d, mm);
      double v = 2.0 * d - e2d[k];
      if (v > best || (v == best && k < bk)) { best = v; bk = k; }
    }
    if (lane == 0) ind[n] = bk;
  }
}

// ---------------- full f64 re-scan, one row per block (rare) ----------------
__global__ void refine_fullC(const float* __restrict__ x, const float* __restrict__ embed,
                             const double* __restrict__ e2d,
                             const int* __restrict__ listC, const uint32_t* __restrict__ cntC,
                             int* __restrict__ ind) {
  __shared__ double xd[DIMS];
  __shared__ double rv[256];
  __shared__ int    rk[256];
  const int tid = threadIdx.x;
  const uint32_t nC = cntC[0];
  for (uint32_t it = blockIdx.x; it < nC; it += gridDim.x) {
    const int n = listC[it];
    __syncthreads();
    xd[tid] = (double)x[(size_t)n * DIMS + tid];
    __syncthreads();
    double best = -1e300; int bk = 0x7fffffff;
    for (int k = tid; k < KCB; k += 256) {
      const float4* er = (const float4*)(embed + (size_t)k * DIMS);
      double a0 = 0.0, a1 = 0.0, a2 = 0.0, a3 = 0.0;   // ILP-4 chains
      for (int c = 0; c < 64; c += 4) {
        float4 ea = er[c], eb = er[c + 1], ec = er[c + 2], ed = er[c + 3];
        int d = c * 4;
        a0 += xd[d + 0] * ea.x + xd[d + 1] * ea.y + xd[d + 2] * ea.z + xd[d + 3] * ea.w;
        a1 += xd[d + 4] * eb.x + xd[d + 5] * eb.y + xd[d + 6] * eb.z + xd[d + 7] * eb.w;
        a2 += xd[d + 8] * ec.x + xd[d + 9] * ec.y + xd[d + 10] * ec.z + xd[d + 11] * ec.w;
        a3 += xd[d + 12] * ed.x + xd[d + 13] * ed.y + xd[d + 14] * ed.z + xd[d + 15] * ed.w;
      }
      double v = 2.0 * (a0 + a1 + a2 + a3) - e2d[k];
      if (v > best || (v == best && k < bk)) { best = v; bk = k; }
    }
    rv[tid] = best; rk[tid] = bk;
    __syncthreads();
    for (int s = 128; s > 0; s >>= 1) {
      if (tid < s) {
        double v2 = rv[tid + s]; int k2 = rk[tid + s];
        if (v2 > rv[tid] || (v2 == rv[tid] && k2 < rk[tid])) { rv[tid] = v2; rk[tid] = k2; }
      }
      __syncthreads();
    }
    if (tid == 0) ind[n] = rk[0];
  }
}

// ---------------- quantize gather + codes + token histogram ----------------
__global__ void gather_q(const float* __restrict__ embed, const int* __restrict__ ind,
                         float* __restrict__ outq, float* __restrict__ outcodes,
                         uint32_t* __restrict__ cntTok) {
  int idx = blockIdx.x * blockDim.x + threadIdx.x;   // over N_TOK*64 float4s
  if (idx >= N_TOK * 64) return;
  int n = idx >> 6, c = idx & 63;
  int k = ind[n];
  ((float4*)outq)[idx] = ((const float4*)embed)[(size_t)k * 64 + c];
  if (c == 0) { outcodes[n] = (float)k; atomicAdd(&cntTok[k], 1u); }
}

// ---------------- scatter token ids into code-major buckets ----------------
__global__ void scatter_tok(const int* __restrict__ ind, const uint32_t* __restrict__ tokBase,
                            uint32_t* __restrict__ cursor, uint32_t* __restrict__ tokBucket) {
  int n = blockIdx.x * blockDim.x + threadIdx.x;
  if (n >= N_TOK) return;
  int k = ind[n];
  uint32_t p = atomicAdd(&cursor[k], 1u);
  tokBucket[tokBase[k] + p] = (uint32_t)n;
}

// ---------------- esum[k] = sum of x rows assigned to k (wave per code) ----------------
__global__ void esum_bucket(const float* __restrict__ x, const uint32_t* __restrict__ tokBase,
                            const uint32_t* __restrict__ cntTok,
                            const uint32_t* __restrict__ tokBucket,
                            float* __restrict__ esum) {
  const uint32_t wv = (blockIdx.x * blockDim.x + threadIdx.x) >> 6;
  if (wv >= KCB) return;
  const int lane = threadIdx.x & 63;
  const uint32_t base = tokBase[wv], cnt = cntTok[wv];
  float4 a0 = {0.f, 0.f, 0.f, 0.f}, a1 = {0.f, 0.f, 0.f, 0.f};
  uint32_t i = 0;
  for (; i + 2 <= cnt; i += 2) {
    uint32_t n0 = tokBucket[base + i], n1 = tokBucket[base + i + 1];
    float4 v0 = ((const float4*)x)[(size_t)n0 * 64 + lane];
    float4 v1 = ((const float4*)x)[(size_t)n1 * 64 + lane];
    a0.x += v0.x; a0.y += v0.y; a0.z += v0.z; a0.w += v0.w;
    a1.x += v1.x; a1.y += v1.y; a1.z += v1.z; a1.w += v1.w;
  }
  if (i < cnt) {
    uint32_t n0 = tokBucket[base + i];
    float4 v0 = ((const float4*)x)[(size_t)n0 * 64 + lane];
    a0.x += v0.x; a0.y += v0.y; a0.z += v0.z; a0.w += v0.w;
  }
  float4 r; r.x = a0.x + a1.x; r.y = a0.y + a1.y; r.z = a0.z + a1.z; r.w = a0.w + a1.w;
  ((float4*)esum)[(size_t)wv * 64 + lane] = r;
}

// ---------------- new_cluster_size + n-sum + expired ----------------
__global__ void ema_stats(const float* __restrict__ cs, const uint32_t* __restrict__ cntTok,
                          float* __restrict__ out_ncs, int* __restrict__ expired,
                          double* __restrict__ nsum) {
  __shared__ double sd[1024];
  int tid = threadIdx.x;
  double local = 0.0;
  for (int k = tid; k < KCB; k += 1024) {
    double v = 0.99 * (double)cs[k] + 0.01 * (double)cntTok[k];
    out_ncs[k] = (float)v;
    expired[k] = (v < 2.0) ? 1 : 0;
    local += v;
  }
  sd[tid] = local; __syncthreads();
  for (int s = 512; s > 0; s >>= 1) { if (tid < s) sd[tid] += sd[tid + s]; __syncthreads(); }
  if (tid == 0) nsum[0] = sd[0];
}

// ---------------- new_embed_avg + new_embed ----------------
__global__ void final_embed(const float* __restrict__ x, const float* __restrict__ cs,
                            const uint32_t* __restrict__ cntTok,
                            const float* __restrict__ eavg, const float* __restrict__ esum,
                            const int* __restrict__ expired, const double* __restrict__ nsum,
                            const uint32_t* __restrict__ perm,
                            float* __restrict__ out_eavg, float* __restrict__ out_ne) {
  int idx = blockIdx.x * blockDim.x + threadIdx.x;   // over KCB*64 float4s
  if (idx >= KCB * 64) return;
  int k = idx >> 6, c = idx & 63;
  float4 ea = ((const float4*)eavg)[idx];
  float4 es = ((const float4*)esum)[idx];
  double ax = 0.99 * (double)ea.x + 0.01 * (double)es.x;
  double ay = 0.99 * (double)ea.y + 0.01 * (double)es.y;
  double az = 0.99 * (double)ea.z + 0.01 * (double)es.z;
  double aw = 0.99 * (double)ea.w + 0.01 * (double)es.w;
  float4 nv; nv.x = (float)ax; nv.y = (float)ay; nv.z = (float)az; nv.w = (float)aw;
  ((float4*)out_eavg)[idx] = nv;
  float4 r;
  if (expired[k]) {
    r = ((const float4*)x)[(size_t)perm[k] * 64 + c];
  } else {
    double ncs = 0.99 * (double)cs[k] + 0.01 * (double)cntTok[k];
    double n = nsum[0];
    double sm = (ncs + 1e-5) / (n + 2048.0 * 1e-5) * n;
    r.x = (float)(ax / sm); r.y = (float)(ay / sm);
    r.z = (float)(az / sm); r.w = (float)(aw / sm);
  }
  ((float4*)out_ne)[idx] = r;
}

// ---------------- permutation pipeline (stable sort by random keys) ----------------
__global__ void keys_round(int round, uint32_t* __restrict__ keys,
                           uint32_t* __restrict__ vals_init, uint32_t* __restrict__ bcount) {
  int i = blockIdx.x * blockDim.x + threadIdx.x;
  if (i >= N_TOK) return;
  uint32_t key = gen_key(round, (uint32_t)i);
  keys[i] = key;
  if (vals_init) vals_init[i] = (uint32_t)i;
  atomicAdd(&bcount[key >> 21], 1u);
}

__global__ void scan2048(const uint32_t* __restrict__ in, uint32_t* __restrict__ out,
                         uint32_t* __restrict__ cursor_zero) {
  __shared__ uint32_t buf[2][2048];
  int t = threadIdx.x;   // 1024
  for (int q = 0; q < 2; ++q) buf[0][t + q * 1024] = in[t + q * 1024];
  cursor_zero[t] = 0; cursor_zero[t + 1024] = 0;
  __syncthreads();
  int src = 0;
  for (int off = 1; off < 2048; off <<= 1) {
    for (int q = 0; q < 2; ++q) {
      int i = t + q * 1024;
      uint32_t v = buf[src][i];
      if (i >= off) v += buf[src][i - off];
      buf[src ^ 1][i] = v;
    }
    src ^= 1; __syncthreads();
  }
  for (int q = 0; q < 2; ++q) {
    int i = t + q * 1024;
    out[i] = buf[src][i] - in[i];   // exclusive
  }
}

__global__ void scatter_buckets(const uint32_t* __restrict__ keys, const uint32_t* __restrict__ vals_in,
                                const uint32_t* __restrict__ bbase, uint32_t* __restrict__ cursor,
                                uint32_t* __restrict__ bkey, uint32_t* __restrict__ bval,
                                uint32_t* __restrict__ bpos) {
  int i = blockIdx.x * blockDim.x + threadIdx.x;
  if (i >= N_TOK) return;
  uint32_t k = keys[i];
  uint32_t b = k >> 21;
  uint32_t p = atomicAdd(&cursor[b], 1u);
  uint32_t s = bbase[b] + p;
  bkey[s] = k; bval[s] = vals_in[i]; bpos[s] = (uint32_t)i;
}

__global__ void rank_buckets(const uint32_t* __restrict__ bkey, const uint32_t* __restrict__ bval,
                             const uint32_t* __restrict__ bpos, const uint32_t* __restrict__ bbase,
                             const uint32_t* __restrict__ bcount, uint32_t* __restrict__ out_vals) {
  int b = blockIdx.x;
  uint32_t base = bbase[b], cnt = bcount[b];
  for (uint32_t t = threadIdx.x; t < cnt; t += blockDim.x) {
    uint32_t k = bkey[base + t], p = bpos[base + t];
    uint32_t r = 0;
    for (uint32_t j = 0; j < cnt; ++j) {
      uint32_t kj = bkey[base + j], pj = bpos[base + j];
      r += (kj < k) | ((kj == k) & (pj < p));
    }
    out_vals[base + r] = bval[base + t];
  }
}

// ---------------- launch ----------------
extern "C" void kernel_launch(void* const* d_in, const int* in_sizes, int n_in,
                              void* d_out, int out_size, void* d_ws, size_t ws_size,
                              hipStream_t stream) {
  const float* x     = (const float*)d_in[0];
  const float* embed = (const float*)d_in[1];
  const float* cs    = (const float*)d_in[2];
  const float* eavg  = (const float*)d_in[3];

  float* out = (float*)d_out;
  float* outQ    = out;                  // 12,288,000
  float* outC    = out + 12288000;       // 48,000
  float* outNCS  = out + 12336000;       // 2,048
  float* outEAVG = out + 12338048;       // 524,288
  float* outNE   = out + 12862336;       // 524,288

  char* w = (char*)d_ws;
  size_t off = 0;
  auto alloc = [&](size_t bytes) -> void* {
    void* p = w + off; off += (bytes + 255) & ~(size_t)255; return p;
  };
  unsigned short* xh = (unsigned short*)alloc((size_t)N_TOK * DIMS * 2);
  unsigned short* eh = (unsigned short*)alloc((size_t)KCB * DIMS * 2);
  float*    e2      = (float*)alloc(KCB * 4);
  double*   e2d     = (double*)alloc(KCB * 8);
  float*    esum    = (float*)alloc((size_t)KCB * DIMS * 4);
  uint32_t* pbest   = (uint32_t*)alloc((size_t)8 * N_TOK * 4);
  uint32_t* psecond = (uint32_t*)alloc((size_t)8 * N_TOK * 4);
  uint32_t* pthird  = (uint32_t*)alloc((size_t)8 * N_TOK * 4);
  int*      ind     = (int*)alloc(N_TOK * 4);
  int*      candRows= (int*)alloc(N_TOK * 4);
  int*      candCnt = (int*)alloc(N_TOK * 4);
  int*      candIdx = (int*)alloc((size_t)N_TOK * 16 * 4);
  int*      listC   = (int*)alloc(N_TOK * 4);
  uint32_t* cntAB   = (uint32_t*)alloc(256);      // [0]=cand rows, [1]=listC
  double*   nsum    = (double*)alloc(256);
  int*      expired = (int*)alloc(KCB * 4);
  uint32_t* cntTok  = (uint32_t*)alloc(KCB * 4);
  uint32_t* tokBase = (uint32_t*)alloc(KCB * 4);
  uint32_t* tokCur  = (uint32_t*)alloc(KCB * 4);
  uint32_t* tokBucket = (uint32_t*)alloc(N_TOK * 4);
  uint32_t* keys    = (uint32_t*)alloc(N_TOK * 4);
  uint32_t* valsA   = (uint32_t*)alloc(N_TOK * 4);
  uint32_t* bkey    = (uint32_t*)alloc(N_TOK * 4);
  uint32_t* bval    = (uint32_t*)alloc(N_TOK * 4);
  uint32_t* bpos    = (uint32_t*)alloc(N_TOK * 4);
  uint32_t* valsB   = (uint32_t*)alloc(N_TOK * 4);
  uint32_t* bcount  = (uint32_t*)alloc(KCB * 4);
  uint32_t* bbase   = (uint32_t*)alloc(KCB * 4);
  uint32_t* cursor  = (uint32_t*)alloc(KCB * 4);

  // zero tie counters, token histogram, bucket counts
  hipMemsetAsync(cntAB, 0, 256, stream);
  hipMemsetAsync(cntTok, 0, KCB * 4, stream);
  hipMemsetAsync(bcount, 0, KCB * 4, stream);

  e2_kernel<<<8, 256, 0, stream>>>(embed, e2, e2d);
  split_both<<<(N_TOK * DIMS / 8 + KCB * DIMS / 8 + 255) / 256, 256, 0, stream>>>(
      x, xh, embed, eh);

  dist_mfma<<<3000, 256, 0, stream>>>(xh, eh, e2, pbest, psecond, pthird);
  merge8<<<188, 256, 0, stream>>>(pbest, psecond, pthird,
                                  ind, candRows, candIdx, candCnt, listC,
                                  &cntAB[0], &cntAB[1]);
  refine_cand<<<512, 256, 0, stream>>>(x, embed, e2d, candRows, candIdx, candCnt,
                                       &cntAB[0], ind);
  refine_fullC<<<1024, 256, 0, stream>>>(x, embed, e2d, listC, &cntAB[1], ind);

  // quantize output + token histogram, then code-major segment sum (no f32 atomics)
  gather_q<<<12000, 256, 0, stream>>>(embed, ind, outQ, outC, cntTok);
  ema_stats<<<1, 1024, 0, stream>>>(cs, cntTok, outNCS, expired, nsum);
  scan2048<<<1, 1024, 0, stream>>>(cntTok, tokBase, tokCur);
  scatter_tok<<<188, 256, 0, stream>>>(ind, tokBase, tokCur, tokBucket);
  esum_bucket<<<512, 256, 0, stream>>>(x, tokBase, cntTok, tokBucket, esum);

  // permutation: round 1 (vals = iota)
  keys_round<<<188, 256, 0, stream>>>(1, keys, valsA, bcount);
  scan2048<<<1, 1024, 0, stream>>>(bcount, bbase, cursor);
  scatter_buckets<<<188, 256, 0, stream>>>(keys, valsA, bbase, cursor, bkey, bval, bpos);
  rank_buckets<<<2048, 64, 0, stream>>>(bkey, bval, bpos, bbase, bcount, valsB);
  // round 2 (vals = round-1 output)
  hipMemsetAsync(bcount, 0, KCB * 4, stream);
  keys_round<<<188, 256, 0, stream>>>(2, keys, nullptr, bcount);
  scan2048<<<1, 1024, 0, stream>>>(bcount, bbase, cursor);
  scatter_buckets<<<188, 256, 0, stream>>>(keys, valsB, bbase, cursor, bkey, bval, bpos);
  rank_buckets<<<2048, 64, 0, stream>>>(bkey, bval, bpos, bbase, bcount, valsA);

  final_embed<<<512, 256, 0, stream>>>(x, cs, cntTok, eavg, esum, expired, nsum,
                                       valsA, outEAVG, outNE);
}

// Round 13
// 262.456 us; speedup vs baseline: 6.3135x; 1.0824x over previous
//
#include <hip/hip_runtime.h>
#include <hip/hip_bf16.h>
#include <stdint.h>
#include <math.h>

// Problem constants
#define N_TOK 48000     // 32*1500
#define DIMS  256
#define KCB   2048
// 1-pass bf16 approx score error: diff std ~6e-3, sub-Gaussian. Packed-u32
// quantization (11 dropped mantissa bits at |score|<32) adds <=0.008/side.
// WND = 0.10 >= 2*delta + 2*quant with >25% margin. True winner's packed
// score >= best - WND. Candidates = per-tile top-2; if a tile's THIRD value
// is in-window the winner may be unstored -> full f64 re-scan for that row.
#define WND 0.10f

typedef __attribute__((ext_vector_type(8))) short bf16x8;
typedef __attribute__((ext_vector_type(4))) float f32x4;
typedef __attribute__((ext_vector_type(8))) unsigned short u16x8;

// ---------------- bf16 helpers (explicit RNE) ----------------
__device__ __forceinline__ unsigned short bf16rn(float f) {
  uint32_t u = __float_as_uint(f);
  uint32_t r = (u + 0x7FFFu + ((u >> 16) & 1u)) >> 16;
  return (unsigned short)r;
}

// ---------------- packed sortable score: high21=monotone f32, low11=2047-k ----------------
__device__ __forceinline__ uint32_t packScore(float f, uint32_t invIdx) {
  uint32_t b = __float_as_uint(f);
  uint32_t m = (uint32_t)((int32_t)b >> 31) | 0x80000000u;
  return ((b ^ m) & ~0x7FFu) | invIdx;
}
__device__ __forceinline__ uint32_t packThr(float f) {
  uint32_t b = __float_as_uint(f);
  uint32_t m = (uint32_t)((int32_t)b >> 31) | 0x80000000u;
  return (b ^ m) & ~0x7FFu;
}
__device__ __forceinline__ float unpackScore(uint32_t u) {
  uint32_t v = u & ~0x7FFu;
  uint32_t b = (v & 0x80000000u) ? (v ^ 0x80000000u) : ~v;
  return __uint_as_float(b);
}
// branch-free sorted top-3 insert (b>=s>=t), 5 u32 min/max ops
__device__ __forceinline__ void ins3u(uint32_t& b, uint32_t& s, uint32_t& t, uint32_t v) {
  uint32_t lo = min(b, v);
  b = max(b, v);
  uint32_t lo2 = min(s, lo);
  s = max(s, lo);
  t = max(t, lo2);
}

// ---------------- Threefry-2x32 (matches jax._src.prng, partitionable) ----------------
__device__ inline void tf2x32(uint32_t k0, uint32_t k1, uint32_t c0, uint32_t c1,
                              uint32_t& o0, uint32_t& o1) {
  uint32_t ks2 = k0 ^ k1 ^ 0x1BD11BDAu;
  uint32_t x0 = c0 + k0, x1 = c1 + k1;
#define TF_R(r) { x0 += x1; x1 = (x1 << (r)) | (x1 >> (32 - (r))); x1 ^= x0; }
  TF_R(13) TF_R(15) TF_R(26) TF_R(6)
  x0 += k1; x1 += ks2 + 1u;
  TF_R(17) TF_R(29) TF_R(16) TF_R(24)
  x0 += ks2; x1 += k0 + 2u;
  TF_R(13) TF_R(15) TF_R(26) TF_R(6)
  x0 += k0; x1 += k1 + 3u;
  TF_R(17) TF_R(29) TF_R(16) TF_R(24)
  x0 += k1; x1 += ks2 + 4u;
  TF_R(13) TF_R(15) TF_R(26) TF_R(6)
  x0 += ks2; x1 += k0 + 5u;
#undef TF_R
  o0 = x0; o1 = x1;
}

__device__ inline void get_round_key(int round, uint32_t& ka, uint32_t& kb) {
  const uint32_t b0 = 0u, b1 = 1u;  // jax.random.key(1) -> (0,1)
  uint32_t K1a, K1b, S1a, S1b;
  tf2x32(b0, b1, 0u, 0u, K1a, K1b);
  tf2x32(b0, b1, 0u, 1u, S1a, S1b);
  if (round == 1) { ka = S1a; kb = S1b; return; }
  uint32_t S2a, S2b;
  tf2x32(K1a, K1b, 0u, 1u, S2a, S2b);
  ka = S2a; kb = S2b;
}

__device__ inline uint32_t gen_key(int round, uint32_t i) {
  uint32_t ka, kb, o0, o1;
  get_round_key(round, ka, kb);
  tf2x32(ka, kb, 0u, i, o0, o1);
  return o0 ^ o1;
}

// ---------------- global_load_lds wrapper (16B) ----------------
__device__ __forceinline__ void gload_lds16(const void* g, void* l) {
  __builtin_amdgcn_global_load_lds(
      (const __attribute__((address_space(1))) uint32_t*)g,
      (__attribute__((address_space(3))) uint32_t*)l, 16, 0, 0);
}

// ---------------- fused: f32->bf16 split (x, embed) + e2 (f32/f64) ----------------
__global__ void e2split(const float* __restrict__ x, unsigned short* __restrict__ xh,
                        const float* __restrict__ embed, unsigned short* __restrict__ eh,
                        float* __restrict__ e2, double* __restrict__ e2d) {
  const int nx = N_TOK * DIMS / 8;
  const int ne = KCB * DIMS / 8;
  int i = blockIdx.x * blockDim.x + threadIdx.x;
  if (i < nx + ne) {
    const float* src; unsigned short* dst; int j;
    if (i < nx) { src = x; dst = xh; j = i; }
    else { src = embed; dst = eh; j = i - nx; }
    float4 a = ((const float4*)src)[j * 2];
    float4 b = ((const float4*)src)[j * 2 + 1];
    float v[8] = {a.x, a.y, a.z, a.w, b.x, b.y, b.z, b.w};
    u16x8 h;
#pragma unroll
    for (int q = 0; q < 8; ++q) h[q] = bf16rn(v[q]);
    *(u16x8*)&dst[(size_t)j * 8] = h;
    return;
  }
  int k = i - (nx + ne);
  if (k < KCB) {
    const float4* er = (const float4*)(embed + (size_t)k * DIMS);
    float s = 0.f;
    double sd = 0.0;
    for (int c = 0; c < DIMS / 4; ++c) {
      float4 v = er[c];
      s = fmaf(v.x, v.x, s); s = fmaf(v.y, v.y, s);
      s = fmaf(v.z, v.z, s); s = fmaf(v.w, v.w, s);
      sd += (double)v.x * v.x + (double)v.y * v.y
          + (double)v.z * v.z + (double)v.w * v.w;
    }
    e2[k] = s;
    e2d[k] = sd;
  }
}

// ---------------- MFMA distance top-3 (single bf16 pass, packed epilogue) ----------------
// approx score = 2*(xh.eh) - e2[k]; 128x256 tile, BK=32, 8 steps,
// double-buffered LDS. Bank swizzle (both-sides involution, rule 21):
// 64B rows = 4 chunks of 16B; physical chunk = logical ^ ((row>>1)&3).
// Epilogue: packed sortable u32 scores, branch-free top-3, LDS table reduce
// (stride 99 -> 2-way banks = free; fold split across all 256 threads).
__global__ __launch_bounds__(256, 2) void dist_mfma(
    const unsigned short* __restrict__ xh, const unsigned short* __restrict__ eh,
    const float* __restrict__ e2,
    uint32_t* __restrict__ pb, uint32_t* __restrict__ ps, uint32_t* __restrict__ pt)
{
  // staging (49152 B) and reduction table (128*99*4 = 50688 B) alias
  __shared__ __align__(16) char smem[50688];
  short (*As)[128 * 32] = (short(*)[128 * 32])smem;            // 2 x 8 KB
  short (*Bs)[256 * 32] = (short(*)[256 * 32])(smem + 16384);  // 2 x 16 KB
  uint32_t* red = (uint32_t*)smem;                             // [128][99] u32

  const int tid = threadIdx.x;
  const int lane = tid & 63, w = tid >> 6;
  const int wr = w >> 1, wc = w & 1;      // wave tile: 64 rows x 128 cols
  const int l15 = lane & 15, lg = lane >> 4;

  // XCD grouping: the 8 y-tiles sharing an x-tile get bids == same (mod 8),
  // spaced 8 apart -> same XCD L2 -> x-tile fetched from HBM once per XCD.
  int bx, by;
  {
    const int bid = blockIdx.x;
    if (bid < 2944) { int g = bid >> 6, r = bid & 63; bx = g * 8 + (r & 7); by = r >> 3; }
    else            { int t2 = bid - 2944; bx = 368 + (t2 % 7); by = t2 / 7; }
  }
  const int n0 = bx * 128;   // token tile base
  const int c0 = by * 256;   // code tile base

  f32x4 acc[4][8];
#pragma unroll
  for (int mf = 0; mf < 4; ++mf)
#pragma unroll
    for (int nf = 0; nf < 8; ++nf) acc[mf][nf] = (f32x4){0.f, 0.f, 0.f, 0.f};

  // stage step t into buffer t&1 (linear LDS dest; source pre-swizzled)
  auto stage = [&](int t) {
    const int d0 = t << 5;     // d-chunk of 32 shorts
    const int q = t & 1;
#pragma unroll
    for (int i = 0; i < 2; ++i) {
      const int c = i * 256 + tid;
      const int row = c >> 2;
      const int sc = ((c & 3) ^ ((row >> 1) & 3)) << 3;   // swizzled source chunk
      gload_lds16(xh + (size_t)(n0 + row) * DIMS + d0 + sc, (void*)&As[q][c * 8]);
    }
#pragma unroll
    for (int i = 0; i < 4; ++i) {
      const int c = i * 256 + tid;
      const int row = c >> 2;
      const int sc = ((c & 3) ^ ((row >> 1) & 3)) << 3;
      gload_lds16(eh + (size_t)(c0 + row) * DIMS + d0 + sc, (void*)&Bs[q][c * 8]);
    }
  };

  stage(0);
  __syncthreads();   // buf0 ready

#pragma unroll 1
  for (int t = 0; t < 8; ++t) {
    if (t < 7) stage(t + 1);         // issue next-step loads (overlap w/ compute)
    const int q = t & 1;
    bf16x8 af[4], bfv[8];
#pragma unroll
    for (int mf = 0; mf < 4; ++mf) {
      const int r = wr * 64 + mf * 16 + l15;
      af[mf] = *(const bf16x8*)&As[q][r * 32 + ((lg ^ ((r >> 1) & 3)) << 3)];
    }
#pragma unroll
    for (int nf = 0; nf < 8; ++nf) {
      const int r = wc * 128 + nf * 16 + l15;
      bfv[nf] = *(const bf16x8*)&Bs[q][r * 32 + ((lg ^ ((r >> 1) & 3)) << 3)];
    }
#pragma unroll
    for (int mf = 0; mf < 4; ++mf)
#pragma unroll
      for (int nf = 0; nf < 8; ++nf)
        acc[mf][nf] = __builtin_amdgcn_mfma_f32_16x16x32_bf16(
            af[mf], bfv[nf], acc[mf][nf], 0, 0, 0);
    __syncthreads();                 // staged loads drained + rw hazards
  }
  // K-loop done; last barrier above makes staging LDS safe to reuse as `red`.

  float e2v[8];
  uint32_t inv[8];
#pragma unroll
  for (int nf = 0; nf < 8; ++nf) {
    int k = c0 + wc * 128 + nf * 16 + l15;
    e2v[nf] = e2[k];
    inv[nf] = 2047u - (uint32_t)k;
  }

  const int colbase = wc * 16 + l15;
#pragma unroll
  for (int mf = 0; mf < 4; ++mf) {
#pragma unroll
    for (int reg = 0; reg < 4; ++reg) {
      uint32_t b = 0u, s = 0u, t3 = 0u;
#pragma unroll
      for (int nf = 0; nf < 8; ++nf) {
        float f = fmaf(2.f, acc[mf][nf][reg], -e2v[nf]);
        ins3u(b, s, t3, packScore(f, inv[nf]));
      }
      const int row = wr * 64 + mf * 16 + lg * 4 + reg;
      uint32_t* p = &red[row * 99 + colbase * 3];
      p[0] = b; p[1] = s; p[2] = t3;
    }
  }
  __syncthreads();
  {
    const int row = tid >> 1, half = tid & 1;
    uint32_t b = 0u, s = 0u, t3 = 0u;
    const uint32_t* p = &red[row * 99 + half * 48];
#pragma unroll 4
    for (int c = 0; c < 48; ++c) ins3u(b, s, t3, p[c]);
    if (half) {
      uint32_t* q = &red[row * 99 + 96];
      q[0] = b; q[1] = s; q[2] = t3;
    }
    __syncthreads();
    if (!half) {
      const uint32_t* q = &red[row * 99 + 96];
      ins3u(b, s, t3, q[0]);
      ins3u(b, s, t3, q[1]);
      ins3u(b, s, t3, q[2]);
      size_t o = (size_t)by * N_TOK + n0 + row;
      pb[o] = b; ps[o] = s; pt[o] = t3;
    }
  }
}

// ---------------- merge 8 column-tile partials + candidate collection ----------------
__global__ void merge8(const uint32_t* __restrict__ pb, const uint32_t* __restrict__ ps,
                       const uint32_t* __restrict__ pt,
                       int* __restrict__ ind,
                       int* __restrict__ candRows, int* __restrict__ candIdx,
                       int* __restrict__ candCnt, int* __restrict__ listC,
                       uint32_t* __restrict__ cntA, uint32_t* __restrict__ cntC) {
  int n = blockIdx.x * blockDim.x + threadIdx.x;
  if (n >= N_TOK) return;
  uint32_t tb[8], tsv[8], ttv[8];
#pragma unroll
  for (int tt = 0; tt < 8; ++tt) {
    size_t o = (size_t)tt * N_TOK + n;
    tb[tt] = pb[o]; tsv[tt] = ps[o]; ttv[tt] = pt[o];
  }
  uint32_t best = tb[0];
#pragma unroll
  for (int tt = 1; tt < 8; ++tt) best = max(best, tb[tt]);
  ind[n] = 2047 - (int)(best & 0x7FFu);   // provisional winner
  const uint32_t thr = packThr(unpackScore(best) - WND);
  int m = 0; bool full = false;
#pragma unroll
  for (int tt = 0; tt < 8; ++tt) {
    m += (tb[tt] >= thr) + (tsv[tt] >= thr);
    full = full || (ttv[tt] >= thr);   // a tile's unstored 3rd+ could be in-window
  }
  if (full) {
    listC[atomicAdd(cntC, 1u)] = n;
  } else if (m > 1) {
    uint32_t i = atomicAdd(cntA, 1u);
    candRows[i] = n; candCnt[i] = m;
    int j = 0;
#pragma unroll
    for (int tt = 0; tt < 8; ++tt) {
      if (tb[tt]  >= thr) candIdx[(size_t)i * 16 + (j++)] = 2047 - (int)(tb[tt]  & 0x7FFu);
      if (tsv[tt] >= thr) candIdx[(size_t)i * 16 + (j++)] = 2047 - (int)(tsv[tt] & 0x7FFu);
    }
  }
}

// ---------------- wave-per-row f64 candidate decider ----------------
__global__ void refine_cand(const float* __restrict__ x, const float* __restrict__ embed,
                            const double* __restrict__ e2d,
                            const int* __restrict__ candRows, const int* __restrict__ candIdx,
                            const int* __restrict__ candCnt, const uint32_t* __restrict__ cntA,
                            int* __restrict__ ind) {
  const uint32_t nA = cntA[0];
  const int lane = threadIdx.x & 63;
  const uint32_t wid = (blockIdx.x * blockDim.x + threadIdx.x) >> 6;
  const uint32_t nw = (gridDim.x * blockDim.x) >> 6;
  for (uint32_t i = wid; i < nA; i += nw) {
    const int n = candRows[i];
    const int m = candCnt[i];
    float4 xv = ((const float4*)x)[(size_t)n * 64 + lane];
    double best = -1e300; int bk = 0x7fffffff;
    for (int j = 0; j < m; ++j) {
      int k = candIdx[(size_t)i * 16 + j];
      float4 e4 = ((const float4*)embed)[(size_t)k * 64 + lane];
      double d = (double)xv.x * e4.x + (double)xv.y * e4.y
               + (double)xv.z * e4.z + (double)xv.w * e4.w;
#pragma unroll
      for (int mm = 1; mm < 64; mm <<= 1) d += __shfl_xor(d, mm);
      double v = 2.0 * d - e2d[k];
      if (v > best || (v == best && k < bk)) { best = v; bk = k; }
    }
    if (lane == 0) ind[n] = bk;
  }
}

// ---------------- full f64 re-scan, one row per block (rare) ----------------
__global__ void refine_fullC(const float* __restrict__ x, const float* __restrict__ embed,
                             const double* __restrict__ e2d,
                             const int* __restrict__ listC, const uint32_t* __restrict__ cntC,
                             int* __restrict__ ind) {
  __shared__ double xd[DIMS];
  __shared__ double rv[256];
  __shared__ int    rk[256];
  const int tid = threadIdx.x;
  const uint32_t nC = cntC[0];
  for (uint32_t it = blockIdx.x; it < nC; it += gridDim.x) {
    const int n = listC[it];
    __syncthreads();
    xd[tid] = (double)x[(size_t)n * DIMS + tid];
    __syncthreads();
    double best = -1e300; int bk = 0x7fffffff;
    for (int k = tid; k < KCB; k += 256) {
      const float4* er = (const float4*)(embed + (size_t)k * DIMS);
      double a0 = 0.0, a1 = 0.0, a2 = 0.0, a3 = 0.0;   // ILP-4 chains
      for (int c = 0; c < 64; c += 4) {
        float4 ea = er[c], eb = er[c + 1], ec = er[c + 2], ed = er[c + 3];
        int d = c * 4;
        a0 += xd[d + 0] * ea.x + xd[d + 1] * ea.y + xd[d + 2] * ea.z + xd[d + 3] * ea.w;
        a1 += xd[d + 4] * eb.x + xd[d + 5] * eb.y + xd[d + 6] * eb.z + xd[d + 7] * eb.w;
        a2 += xd[d + 8] * ec.x + xd[d + 9] * ec.y + xd[d + 10] * ec.z + xd[d + 11] * ec.w;
        a3 += xd[d + 12] * ed.x + xd[d + 13] * ed.y + xd[d + 14] * ed.z + xd[d + 15] * ed.w;
      }
      double v = 2.0 * (a0 + a1 + a2 + a3) - e2d[k];
      if (v > best || (v == best && k < bk)) { best = v; bk = k; }
    }
    rv[tid] = best; rk[tid] = bk;
    __syncthreads();
    for (int s = 128; s > 0; s >>= 1) {
      if (tid < s) {
        double v2 = rv[tid + s]; int k2 = rk[tid + s];
        if (v2 > rv[tid] || (v2 == rv[tid] && k2 < rk[tid])) { rv[tid] = v2; rk[tid] = k2; }
      }
      __syncthreads();
    }
    if (tid == 0) ind[n] = rk[0];
  }
}

// ---------------- quantize gather + codes + token histogram ----------------
__global__ void gather_q(const float* __restrict__ embed, const int* __restrict__ ind,
                         float* __restrict__ outq, float* __restrict__ outcodes,
                         uint32_t* __restrict__ cntTok) {
  int idx = blockIdx.x * blockDim.x + threadIdx.x;   // over N_TOK*64 float4s
  if (idx >= N_TOK * 64) return;
  int n = idx >> 6, c = idx & 63;
  int k = ind[n];
  ((float4*)outq)[idx] = ((const float4*)embed)[(size_t)k * 64 + c];
  if (c == 0) { outcodes[n] = (float)k; atomicAdd(&cntTok[k], 1u); }
}

// ---------------- token-count scan + EMA stats (fused, 1 block) ----------------
__global__ void scan_tok_ema(const uint32_t* __restrict__ cntTok, uint32_t* __restrict__ tokBase,
                             uint32_t* __restrict__ tokCur,
                             const float* __restrict__ cs, float* __restrict__ out_ncs,
                             int* __restrict__ expired, double* __restrict__ nsum) {
  __shared__ uint32_t buf[2][2048];
  __shared__ double sd[1024];
  int t = threadIdx.x;   // 1024
  double local = 0.0;
  for (int q = 0; q < 2; ++q) {
    int i = t + q * 1024;
    uint32_t c = cntTok[i];
    buf[0][i] = c;
    tokCur[i] = 0;
    double v = 0.99 * (double)cs[i] + 0.01 * (double)c;
    out_ncs[i] = (float)v;
    expired[i] = (v < 2.0) ? 1 : 0;
    local += v;
  }
  sd[t] = local;
  __syncthreads();
  int src = 0;
  for (int off = 1; off < 2048; off <<= 1) {
    for (int q = 0; q < 2; ++q) {
      int i = t + q * 1024;
      uint32_t v = buf[src][i];
      if (i >= off) v += buf[src][i - off];
      buf[src ^ 1][i] = v;
    }
    src ^= 1; __syncthreads();
  }
  for (int q = 0; q < 2; ++q) {
    int i = t + q * 1024;
    tokBase[i] = buf[src][i] - cntTok[i];   // exclusive
  }
  for (int s = 512; s > 0; s >>= 1) { if (t < s) sd[t] += sd[t + s]; __syncthreads(); }
  if (t == 0) nsum[0] = sd[0];
}

// ---------------- scatter token ids into code-major buckets ----------------
__global__ void scatter_tok(const int* __restrict__ ind, const uint32_t* __restrict__ tokBase,
                            uint32_t* __restrict__ cursor, uint32_t* __restrict__ tokBucket) {
  int n = blockIdx.x * blockDim.x + threadIdx.x;
  if (n >= N_TOK) return;
  int k = ind[n];
  uint32_t p = atomicAdd(&cursor[k], 1u);
  tokBucket[tokBase[k] + p] = (uint32_t)n;
}

// ---------------- esum[k] = sum of x rows assigned to k (wave per code) ----------------
__global__ void esum_bucket(const float* __restrict__ x, const uint32_t* __restrict__ tokBase,
                            const uint32_t* __restrict__ cntTok,
                            const uint32_t* __restrict__ tokBucket,
                            float* __restrict__ esum) {
  const uint32_t wv = (blockIdx.x * blockDim.x + threadIdx.x) >> 6;
  if (wv >= KCB) return;
  const int lane = threadIdx.x & 63;
  const uint32_t base = tokBase[wv], cnt = cntTok[wv];
  float4 a0 = {0.f, 0.f, 0.f, 0.f}, a1 = {0.f, 0.f, 0.f, 0.f};
  uint32_t i = 0;
  for (; i + 2 <= cnt; i += 2) {
    uint32_t n0 = tokBucket[base + i], n1 = tokBucket[base + i + 1];
    float4 v0 = ((const float4*)x)[(size_t)n0 * 64 + lane];
    float4 v1 = ((const float4*)x)[(size_t)n1 * 64 + lane];
    a0.x += v0.x; a0.y += v0.y; a0.z += v0.z; a0.w += v0.w;
    a1.x += v1.x; a1.y += v1.y; a1.z += v1.z; a1.w += v1.w;
  }
  if (i < cnt) {
    uint32_t n0 = tokBucket[base + i];
    float4 v0 = ((const float4*)x)[(size_t)n0 * 64 + lane];
    a0.x += v0.x; a0.y += v0.y; a0.z += v0.z; a0.w += v0.w;
  }
  float4 r; r.x = a0.x + a1.x; r.y = a0.y + a1.y; r.z = a0.z + a1.z; r.w = a0.w + a1.w;
  ((float4*)esum)[(size_t)wv * 64 + lane] = r;
}

// ---------------- new_embed_avg + new_embed ----------------
__global__ void final_embed(const float* __restrict__ x, const float* __restrict__ cs,
                            const uint32_t* __restrict__ cntTok,
                            const float* __restrict__ eavg, const float* __restrict__ esum,
                            const int* __restrict__ expired, const double* __restrict__ nsum,
                            const uint32_t* __restrict__ perm,
                            float* __restrict__ out_eavg, float* __restrict__ out_ne) {
  int idx = blockIdx.x * blockDim.x + threadIdx.x;   // over KCB*64 float4s
  if (idx >= KCB * 64) return;
  int k = idx >> 6, c = idx & 63;
  float4 ea = ((const float4*)eavg)[idx];
  float4 es = ((const float4*)esum)[idx];
  double ax = 0.99 * (double)ea.x + 0.01 * (double)es.x;
  double ay = 0.99 * (double)ea.y + 0.01 * (double)es.y;
  double az = 0.99 * (double)ea.z + 0.01 * (double)es.z;
  double aw = 0.99 * (double)ea.w + 0.01 * (double)es.w;
  float4 nv; nv.x = (float)ax; nv.y = (float)ay; nv.z = (float)az; nv.w = (float)aw;
  ((float4*)out_eavg)[idx] = nv;
  float4 r;
  if (expired[k]) {
    r = ((const float4*)x)[(size_t)perm[k] * 64 + c];
  } else {
    double ncs = 0.99 * (double)cs[k] + 0.01 * (double)cntTok[k];
    double n = nsum[0];
    double sm = (ncs + 1e-5) / (n + 2048.0 * 1e-5) * n;
    r.x = (float)(ax / sm); r.y = (float)(ay / sm);
    r.z = (float)(az / sm); r.w = (float)(aw / sm);
  }
  ((float4*)out_ne)[idx] = r;
}

// ---------------- permutation pipeline (stable sort by random keys) ----------------
// Both rounds' keys are pure functions of the index -> compute together.
__global__ void keys_both(uint32_t* __restrict__ keys1, uint32_t* __restrict__ keys2,
                          uint32_t* __restrict__ bcount1, uint32_t* __restrict__ bcount2) {
  int i = blockIdx.x * blockDim.x + threadIdx.x;
  if (i >= N_TOK) return;
  uint32_t k1 = gen_key(1, (uint32_t)i);
  uint32_t k2 = gen_key(2, (uint32_t)i);
  keys1[i] = k1; keys2[i] = k2;
  atomicAdd(&bcount1[k1 >> 21], 1u);
  atomicAdd(&bcount2[k2 >> 21], 1u);
}

// block 0 scans hist1 (+zero cursor1), block 1 scans hist2 (+zero cursor2)
__global__ void scan_both(const uint32_t* __restrict__ in1, uint32_t* __restrict__ out1,
                          uint32_t* __restrict__ cur1,
                          const uint32_t* __restrict__ in2, uint32_t* __restrict__ out2,
                          uint32_t* __restrict__ cur2) {
  const uint32_t* in = blockIdx.x ? in2 : in1;
  uint32_t* out = blockIdx.x ? out2 : out1;
  uint32_t* cz = blockIdx.x ? cur2 : cur1;
  __shared__ uint32_t buf[2][2048];
  int t = threadIdx.x;   // 1024
  for (int q = 0; q < 2; ++q) buf[0][t + q * 1024] = in[t + q * 1024];
  cz[t] = 0; cz[t + 1024] = 0;
  __syncthreads();
  int src = 0;
  for (int off = 1; off < 2048; off <<= 1) {
    for (int q = 0; q < 2; ++q) {
      int i = t + q * 1024;
      uint32_t v = buf[src][i];
      if (i >= off) v += buf[src][i - off];
      buf[src ^ 1][i] = v;
    }
    src ^= 1; __syncthreads();
  }
  for (int q = 0; q < 2; ++q) {
    int i = t + q * 1024;
    out[i] = buf[src][i] - in[i];   // exclusive
  }
}

// round-1 scatter: value == original position (input is iota)
__global__ void scatter1(const uint32_t* __restrict__ keys1, const uint32_t* __restrict__ bbase1,
                         uint32_t* __restrict__ cursor1,
                         uint32_t* __restrict__ bkey, uint32_t* __restrict__ bval) {
  int i = blockIdx.x * blockDim.x + threadIdx.x;
  if (i >= N_TOK) return;
  uint32_t k = keys1[i];
  uint32_t b = k >> 21;
  uint32_t p = atomicAdd(&cursor1[b], 1u);
  uint32_t s = bbase1[b] + p;
  bkey[s] = k; bval[s] = (uint32_t)i;   // value == tie-break position for round 1
}

// rank round-1 elements (stable by (key,pos)) and scatter directly into
// round-2 buckets: sorted position p gets round-2 key keys2[p].
__global__ void rank1_scatter2(const uint32_t* __restrict__ bkey, const uint32_t* __restrict__ bval,
                               const uint32_t* __restrict__ bbase1, const uint32_t* __restrict__ bcount1,
                               const uint32_t* __restrict__ keys2,
                               const uint32_t* __restrict__ bbase2, uint32_t* __restrict__ cursor2,
                               uint32_t* __restrict__ bkey2, uint32_t* __restrict__ bval2,
                               uint32_t* __restrict__ bpos2) {
  int b = blockIdx.x;
  uint32_t base = bbase1[b], cnt = bcount1[b];
  for (uint32_t t = threadIdx.x; t < cnt; t += blockDim.x) {
    uint32_t k = bkey[base + t], pv = bval[base + t];
    uint32_t r = 0;
    for (uint32_t j = 0; j < cnt; ++j) {
      uint32_t kj = bkey[base + j], pj = bval[base + j];
      r += (kj < k) | ((kj == k) & (pj < pv));
    }
    uint32_t p = base + r;          // global round-1 sorted position
    uint32_t k2 = keys2[p];
    uint32_t b2 = k2 >> 21;
    uint32_t q = atomicAdd(&cursor2[b2], 1u);
    uint32_t s = bbase2[b2] + q;
    bkey2[s] = k2; bval2[s] = pv; bpos2[s] = p;
  }
}

// round-2 rank; only output positions < KCB are consumed (perm[0..2047])
__global__ void rank2(const uint32_t* __restrict__ bkey2, const uint32_t* __restrict__ bval2,
                      const uint32_t* __restrict__ bpos2,
                      const uint32_t* __restrict__ bbase2, const uint32_t* __restrict__ bcount2,
                      uint32_t* __restrict__ perm) {
  int b = blockIdx.x;
  uint32_t base = bbase2[b];
  if (base >= KCB) return;          // every element lands at position >= 2048
  uint32_t cnt = bcount2[b];
  for (uint32_t t = threadIdx.x; t < cnt; t += blockDim.x) {
    uint32_t k = bkey2[base + t], p = bpos2[base + t];
    uint32_t r = 0;
    for (uint32_t j = 0; j < cnt; ++j) {
      uint32_t kj = bkey2[base + j], pj = bpos2[base + j];
      r += (kj < k) | ((kj == k) & (pj < p));
    }
    uint32_t pos = base + r;
    if (pos < KCB) perm[pos] = bval2[base + t];
  }
}

// ---------------- launch ----------------
extern "C" void kernel_launch(void* const* d_in, const int* in_sizes, int n_in,
                              void* d_out, int out_size, void* d_ws, size_t ws_size,
                              hipStream_t stream) {
  const float* x     = (const float*)d_in[0];
  const float* embed = (const float*)d_in[1];
  const float* cs    = (const float*)d_in[2];
  const float* eavg  = (const float*)d_in[3];

  float* out = (float*)d_out;
  float* outQ    = out;                  // 12,288,000
  float* outC    = out + 12288000;       // 48,000
  float* outNCS  = out + 12336000;       // 2,048
  float* outEAVG = out + 12338048;       // 524,288
  float* outNE   = out + 12862336;       // 524,288

  char* w = (char*)d_ws;
  size_t off = 0;
  auto alloc = [&](size_t bytes) -> void* {
    void* p = w + off; off += (bytes + 255) & ~(size_t)255; return p;
  };
  unsigned short* xh = (unsigned short*)alloc((size_t)N_TOK * DIMS * 2);
  unsigned short* eh = (unsigned short*)alloc((size_t)KCB * DIMS * 2);
  float*    e2      = (float*)alloc(KCB * 4);
  double*   e2d     = (double*)alloc(KCB * 8);
  float*    esum    = (float*)alloc((size_t)KCB * DIMS * 4);
  uint32_t* pbest   = (uint32_t*)alloc((size_t)8 * N_TOK * 4);
  uint32_t* psecond = (uint32_t*)alloc((size_t)8 * N_TOK * 4);
  uint32_t* pthird  = (uint32_t*)alloc((size_t)8 * N_TOK * 4);
  int*      ind     = (int*)alloc(N_TOK * 4);
  int*      candRows= (int*)alloc(N_TOK * 4);
  int*      candCnt = (int*)alloc(N_TOK * 4);
  int*      candIdx = (int*)alloc((size_t)N_TOK * 16 * 4);
  int*      listC   = (int*)alloc(N_TOK * 4);
  double*   nsum    = (double*)alloc(256);
  int*      expired = (int*)alloc(KCB * 4);
  uint32_t* tokBase = (uint32_t*)alloc(KCB * 4);
  uint32_t* tokCur  = (uint32_t*)alloc(KCB * 4);
  uint32_t* tokBucket = (uint32_t*)alloc(N_TOK * 4);
  uint32_t* keys1   = (uint32_t*)alloc(N_TOK * 4);
  uint32_t* keys2   = (uint32_t*)alloc(N_TOK * 4);
  uint32_t* bkey    = (uint32_t*)alloc(N_TOK * 4);
  uint32_t* bval    = (uint32_t*)alloc(N_TOK * 4);
  uint32_t* bkey2   = (uint32_t*)alloc(N_TOK * 4);
  uint32_t* bval2   = (uint32_t*)alloc(N_TOK * 4);
  uint32_t* bpos2   = (uint32_t*)alloc(N_TOK * 4);
  uint32_t* bbase1  = (uint32_t*)alloc(KCB * 4);
  uint32_t* bbase2  = (uint32_t*)alloc(KCB * 4);
  uint32_t* cursor1 = (uint32_t*)alloc(KCB * 4);
  uint32_t* cursor2 = (uint32_t*)alloc(KCB * 4);
  uint32_t* perm    = (uint32_t*)alloc(KCB * 4);
  // contiguous zero region: cntAB(256) | cntTok | bcount1 | bcount2
  uint32_t* cntAB   = (uint32_t*)alloc(256);
  uint32_t* cntTok  = (uint32_t*)alloc(KCB * 4);
  uint32_t* bcount1 = (uint32_t*)alloc(KCB * 4);
  uint32_t* bcount2 = (uint32_t*)alloc(KCB * 4);

  hipMemsetAsync(cntAB, 0, 256 + 3 * KCB * 4, stream);   // one memset for all counters

  e2split<<<(N_TOK * DIMS / 8 + KCB * DIMS / 8 + KCB + 255) / 256, 256, 0, stream>>>(
      x, xh, embed, eh, e2, e2d);

  // permutation keys/histograms (independent of main pipeline)
  keys_both<<<188, 256, 0, stream>>>(keys1, keys2, bcount1, bcount2);
  scan_both<<<2, 1024, 0, stream>>>(bcount1, bbase1, cursor1, bcount2, bbase2, cursor2);

  dist_mfma<<<3000, 256, 0, stream>>>(xh, eh, e2, pbest, psecond, pthird);
  merge8<<<188, 256, 0, stream>>>(pbest, psecond, pthird,
                                  ind, candRows, candIdx, candCnt, listC,
                                  &cntAB[0], &cntAB[1]);
  refine_cand<<<512, 256, 0, stream>>>(x, embed, e2d, candRows, candIdx, candCnt,
                                       &cntAB[0], ind);
  refine_fullC<<<1024, 256, 0, stream>>>(x, embed, e2d, listC, &cntAB[1], ind);

  // quantize output + token histogram, then code-major segment sum (no f32 atomics)
  gather_q<<<12000, 256, 0, stream>>>(embed, ind, outQ, outC, cntTok);
  scan_tok_ema<<<1, 1024, 0, stream>>>(cntTok, tokBase, tokCur, cs, outNCS, expired, nsum);
  scatter_tok<<<188, 256, 0, stream>>>(ind, tokBase, tokCur, tokBucket);
  esum_bucket<<<512, 256, 0, stream>>>(x, tokBase, cntTok, tokBucket, esum);

  // permutation: scatter1 -> rank1(+scatter2 fused) -> rank2 (first 2048 only)
  scatter1<<<188, 256, 0, stream>>>(keys1, bbase1, cursor1, bkey, bval);
  rank1_scatter2<<<2048, 64, 0, stream>>>(bkey, bval, bbase1, bcount1,
                                          keys2, bbase2, cursor2, bkey2, bval2, bpos2);
  rank2<<<2048, 64, 0, stream>>>(bkey2, bval2, bpos2, bbase2, bcount2, perm);

  final_embed<<<512, 256, 0, stream>>>(x, cs, cntTok, eavg, esum, expired, nsum,
                                       perm, outEAVG, outNE);
}